// Round 13
// baseline (948.301 us; speedup 1.0000x reference)
//
#include <hip/hip_runtime.h>
#include <hip/hip_fp16.h>
#include <hip/hip_cooperative_groups.h>

namespace cg = cooperative_groups;

#define HID 64
#define NGRAPHS 256
#define CHUNK 8192        // edges per pass-1 chunk
#define BKTSZ 512         // nodes per coarse bucket
#define BKTSH 9
#define PSH 17            // src fits in 17 bits (N <= 131072)
#define PMASK 0x1FFFF

typedef _Float16 half8 __attribute__((ext_vector_type(8)));
typedef float f32x4 __attribute__((ext_vector_type(4)));

// R6-R9: scattered global atomics write through ~64B lines at ~0.9 TB/s
// (memory-side, parallelism-invariant) -> CSR build = LDS counting sort.
// R11: kernel boundaries cost ~6-7us each -> cooperative mega-kernel.
// R12: coop grid sized by occupancy QUERY + return-code-checked, with
// discrete-kernel fallback (R11 path) sharing the same phase bodies.

struct Args {
    const float* x; const int* src; const int* dst; const int* batch;
    const float* W1; const float* b1; const float* W2; const float* b2;
    const float* W3; const float* b3; const float* Wl; const float* bl;
    float* out;
    int N, E, nbkt, nchunk, nscan;
    int* H; int* Hs; int* bsum; int* packed; int* csr; int* rowptr;
    float* dinv; __half* Wf2; __half* Wf3; __half* bufH; __half* bufA;
};

union SMem {
    struct { int cnt[256]; } p0;
    struct { int sh[256]; } p1;
    struct { int off[256]; int lc[256]; int bpref[32]; } p2;
    struct { int cnt[BKTSZ]; int pref[BKTSZ]; int ssum[256]; int cnt2[BKTSZ]; int bpref[32]; } p3;
    struct { float Wsh[7 * HID]; float Ash[16 * 7]; } p4;
    struct { float red[4][64]; float hd[128]; } p10;
};

__device__ __forceinline__ float4 h4_to_f4(int2 raw) {
    __half2 p0 = *(__half2*)&raw.x;
    __half2 p1 = *(__half2*)&raw.y;
    float2 f0 = __half22float2(p0);
    float2 f1 = __half22float2(p1);
    return make_float4(f0.x, f0.y, f1.x, f1.y);
}

// ===== P0: prepW (first 2 blocks) + coarse histogram ======================
__device__ void phase0(const Args& a, SMem& sm) {
    const int t = threadIdx.x;
    const int gtid = blockIdx.x * 256 + t;
    if (gtid < 512) {
        int p = gtid;
        int kt = p >> 8, c = (p >> 6) & 3, lane = p & 63;
        int quad = lane >> 4, m = lane & 15;
#pragma unroll
        for (int j = 0; j < 8; ++j) {
            int k = kt * 32 + quad * 8 + j;
            int ch = c * 16 + m;
            a.Wf2[(size_t)p * 8 + j] = __float2half(a.W2[k * HID + ch]);
            a.Wf3[(size_t)p * 8 + j] = __float2half(a.W3[k * HID + ch]);
        }
    }
    for (int ch = blockIdx.x; ch < a.nchunk; ch += gridDim.x) {
        for (int i = t; i < a.nbkt; i += 256) sm.p0.cnt[i] = 0;
        __syncthreads();
#pragma unroll
        for (int it = 0; it < CHUNK / 1024; ++it) {
            int idx = ch * CHUNK + it * 1024 + t * 4;
            if (idx + 3 < a.E) {
                int4 d = *(const int4*)(a.dst + idx);
                atomicAdd(&sm.p0.cnt[d.x >> BKTSH], 1);
                atomicAdd(&sm.p0.cnt[d.y >> BKTSH], 1);
                atomicAdd(&sm.p0.cnt[d.z >> BKTSH], 1);
                atomicAdd(&sm.p0.cnt[d.w >> BKTSH], 1);
            } else {
                for (int i = idx; i < a.E && i < idx + 4; ++i)
                    atomicAdd(&sm.p0.cnt[a.dst[i] >> BKTSH], 1);
            }
        }
        __syncthreads();
        for (int i = t; i < a.nbkt; i += 256) a.H[i * a.nchunk + ch] = sm.p0.cnt[i];
        __syncthreads();
    }
}

// ===== P1: per-1024 partial exclusive scans + block sums ==================
__device__ void phase1(const Args& a, SMem& sm) {
    const int t = threadIdx.x;
    const int lenH = a.nbkt * a.nchunk;
    for (int sb = blockIdx.x; sb < a.nscan; sb += gridDim.x) {
        int base = sb * 1024 + t * 4;
        int v[4];
        int s = 0;
#pragma unroll
        for (int k = 0; k < 4; k++) {
            int i = base + k;
            v[k] = (i < lenH) ? a.H[i] : 0;
            s += v[k];
        }
        sm.p1.sh[t] = s;
        __syncthreads();
#pragma unroll
        for (int off = 1; off < 256; off <<= 1) {
            int add = (t >= off) ? sm.p1.sh[t - off] : 0;
            __syncthreads();
            sm.p1.sh[t] += add;
            __syncthreads();
        }
        int run = sm.p1.sh[t] - s;
#pragma unroll
        for (int k = 0; k < 4; k++) {
            int i = base + k;
            if (i < lenH) a.Hs[i] = run;
            run += v[k];
        }
        if (t == 255) a.bsum[sb] = sm.p1.sh[255];
        __syncthreads();
    }
}

// ===== P2: bucket scatter (packed 4B, coalesced runs) =====================
__device__ void phase2(const Args& a, SMem& sm) {
    const int t = threadIdx.x;
    if (t == 0) {
        int run = 0;
        for (int i = 0; i < a.nscan; ++i) { sm.p2.bpref[i] = run; run += a.bsum[i]; }
    }
    __syncthreads();
    for (int ch = blockIdx.x; ch < a.nchunk; ch += gridDim.x) {
        for (int i = t; i < a.nbkt; i += 256) {
            int idx = i * a.nchunk + ch;
            sm.p2.off[i] = a.Hs[idx] + sm.p2.bpref[idx >> 10];
            sm.p2.lc[i] = 0;
        }
        __syncthreads();
#pragma unroll
        for (int it = 0; it < CHUNK / 1024; ++it) {
            int idx = ch * CHUNK + it * 1024 + t * 4;
            if (idx + 3 < a.E) {
                int4 d = *(const int4*)(a.dst + idx);
                int4 s = *(const int4*)(a.src + idx);
                int b0 = d.x >> BKTSH, b1 = d.y >> BKTSH;
                int b2 = d.z >> BKTSH, b3 = d.w >> BKTSH;
                int r0 = atomicAdd(&sm.p2.lc[b0], 1);
                int r1 = atomicAdd(&sm.p2.lc[b1], 1);
                int r2 = atomicAdd(&sm.p2.lc[b2], 1);
                int r3 = atomicAdd(&sm.p2.lc[b3], 1);
                a.packed[sm.p2.off[b0] + r0] = s.x | ((d.x & (BKTSZ - 1)) << PSH);
                a.packed[sm.p2.off[b1] + r1] = s.y | ((d.y & (BKTSZ - 1)) << PSH);
                a.packed[sm.p2.off[b2] + r2] = s.z | ((d.z & (BKTSZ - 1)) << PSH);
                a.packed[sm.p2.off[b3] + r3] = s.w | ((d.w & (BKTSZ - 1)) << PSH);
            } else {
                for (int i = idx; i < a.E && i < idx + 4; ++i) {
                    int dd = a.dst[i];
                    int bk = dd >> BKTSH;
                    int r = atomicAdd(&sm.p2.lc[bk], 1);
                    a.packed[sm.p2.off[bk] + r] = a.src[i] | ((dd & (BKTSZ - 1)) << PSH);
                }
            }
        }
        __syncthreads();
    }
}

// ===== P3: per-bucket local CSR build =====================================
__device__ void phase3(const Args& a, SMem& sm) {
    const int t = threadIdx.x;
    if (t == 0) {
        int run = 0;
        for (int i = 0; i < a.nscan; ++i) { sm.p3.bpref[i] = run; run += a.bsum[i]; }
    }
    if (blockIdx.x == 0 && t == 0) a.rowptr[a.N] = a.E;
    __syncthreads();
    for (int bkt = blockIdx.x; bkt < a.nbkt; bkt += gridDim.x) {
        int i0 = bkt * a.nchunk;
        int segStart = a.Hs[i0] + sm.p3.bpref[i0 >> 10];
        int segEnd = a.E;
        if (bkt + 1 < a.nbkt) {
            int i1 = (bkt + 1) * a.nchunk;
            segEnd = a.Hs[i1] + sm.p3.bpref[i1 >> 10];
        }
        sm.p3.cnt[t] = 0; sm.p3.cnt[t + 256] = 0;
        sm.p3.cnt2[t] = 0; sm.p3.cnt2[t + 256] = 0;
        __syncthreads();
        for (int j = segStart + t; j < segEnd; j += 256)
            atomicAdd(&sm.p3.cnt[(a.packed[j] >> PSH) & (BKTSZ - 1)], 1);
        __syncthreads();
        int a0 = sm.p3.cnt[2 * t], a1 = sm.p3.cnt[2 * t + 1];
        int s = a0 + a1;
        sm.p3.ssum[t] = s;
        __syncthreads();
#pragma unroll
        for (int off = 1; off < 256; off <<= 1) {
            int add = (t >= off) ? sm.p3.ssum[t - off] : 0;
            __syncthreads();
            sm.p3.ssum[t] += add;
            __syncthreads();
        }
        int p = sm.p3.ssum[t] - s;
        sm.p3.pref[2 * t] = p;
        sm.p3.pref[2 * t + 1] = p + a0;
        __syncthreads();
        for (int i = t; i < BKTSZ; i += 256) {
            int node = bkt * BKTSZ + i;
            if (node < a.N) {
                a.rowptr[node] = segStart + sm.p3.pref[i];
                a.dinv[node] = rsqrtf((float)(sm.p3.cnt[i] + 1));   // +self
            }
        }
        for (int j = segStart + t; j < segEnd; j += 256) {
            int pk = a.packed[j];
            int ld = (pk >> PSH) & (BKTSZ - 1);
            int r = atomicAdd(&sm.p3.cnt2[ld], 1);
            a.csr[segStart + sm.p3.pref[ld] + r] = pk & PMASK;
        }
        __syncthreads();
    }
}

// ===== P4: layer-1 gemm (K=7, fp32 in): h' = (x @ W1) * dinv ==============
__device__ void phase4(const Args& a, SMem& sm) {
    const int t = threadIdx.x;
    for (int i = t; i < 7 * HID; i += 256) sm.p4.Wsh[i] = a.W1[i];
    __syncthreads();
    const int ntile = (a.N + 15) >> 4;
    for (int tile = blockIdx.x; tile < ntile; tile += gridDim.x) {
        int n0 = tile * 16;
        const long long lim = (long long)(a.N - n0) * 7;
        __syncthreads();
        for (int i = t; i < 16 * 7; i += 256)
            sm.p4.Ash[i] = (i < lim) ? a.x[(size_t)n0 * 7 + i] : 0.0f;
        __syncthreads();
        const int c = t & 63;
        const int g = t >> 6;
        float acc[4] = {0.0f, 0.0f, 0.0f, 0.0f};
#pragma unroll
        for (int k = 0; k < 7; k++) {
            float w = sm.p4.Wsh[k * HID + c];
#pragma unroll
            for (int i = 0; i < 4; i++) acc[i] += sm.p4.Ash[(g * 4 + i) * 7 + k] * w;
        }
#pragma unroll
        for (int i = 0; i < 4; i++) {
            int n = n0 + g * 4 + i;
            if (n < a.N)
                a.bufH[(size_t)n * HID + c] = __float2half(acc[i] * a.dinv[n]);
        }
    }
}

// ===== aggregate: 16 nodes/tile, 16 lanes/node, 8-wide gathers ============
__device__ void agg_phase(const Args& a, const __half* h, const float* b,
                          __half* agg) {
    const int t = threadIdx.x;
    const int ntile = (a.N + 15) >> 4;
    const int2* h8 = (const int2*)h;
    const float4* b4 = (const float4*)b;
    const int l16 = t & 15;
    for (int tile = blockIdx.x; tile < ntile; tile += gridDim.x) {
        int node = tile * 16 + (t >> 4);
        if (node >= a.N) continue;
        int beg = a.rowptr[node], end = a.rowptr[node + 1];
        float dv = a.dinv[node];
        float4 inner = h4_to_f4(h8[(size_t)node * 16 + l16]);   // self h'
        int j = beg;
        for (; j + 7 < end; j += 8) {
            int s[8];
#pragma unroll
            for (int q = 0; q < 8; ++q) s[q] = a.csr[j + q];
            int2 r[8];
#pragma unroll
            for (int q = 0; q < 8; ++q) r[q] = h8[(size_t)s[q] * 16 + l16];
#pragma unroll
            for (int q = 0; q < 8; ++q) {
                float4 v = h4_to_f4(r[q]);
                inner.x += v.x; inner.y += v.y; inner.z += v.z; inner.w += v.w;
            }
        }
        for (; j + 3 < end; j += 4) {
            int s0 = a.csr[j], s1 = a.csr[j + 1];
            int s2 = a.csr[j + 2], s3 = a.csr[j + 3];
            float4 v0 = h4_to_f4(h8[(size_t)s0 * 16 + l16]);
            float4 v1 = h4_to_f4(h8[(size_t)s1 * 16 + l16]);
            float4 v2 = h4_to_f4(h8[(size_t)s2 * 16 + l16]);
            float4 v3 = h4_to_f4(h8[(size_t)s3 * 16 + l16]);
            inner.x += v0.x + v1.x + v2.x + v3.x;
            inner.y += v0.y + v1.y + v2.y + v3.y;
            inner.z += v0.z + v1.z + v2.z + v3.z;
            inner.w += v0.w + v1.w + v2.w + v3.w;
        }
        for (; j < end; j++) {
            float4 v = h4_to_f4(h8[(size_t)a.csr[j] * 16 + l16]);
            inner.x += v.x; inner.y += v.y; inner.z += v.z; inner.w += v.w;
        }
        float4 bb = b4[l16];
        __half2 q0 = __floats2half2_rn(bb.x + dv * inner.x, bb.y + dv * inner.y);
        __half2 q1 = __floats2half2_rn(bb.z + dv * inner.z, bb.w + dv * inner.w);
        int2 outv;
        outv.x = *(int*)&q0;
        outv.y = *(int*)&q1;
        ((int2*)agg)[(size_t)node * 16 + l16] = outv;
    }
}

// ===== MFMA gemm: 64 nodes/tile, 16/wave: h' = (relu(act)@W) * dinv =======
__device__ void mfma_phase(const Args& a, const __half* act, const __half* Wf,
                           __half* h) {
    const int t = threadIdx.x;
    const int wave = t >> 6, lane = t & 63;
    const int quad = lane >> 4, m = lane & 15;
    const int ntile = (a.N + 63) >> 6;
    const half8* Wf8 = (const half8*)Wf;
    for (int tile = blockIdx.x; tile < ntile; tile += gridDim.x) {
        int n0 = tile * 64 + wave * 16;
        if (n0 >= a.N) continue;            // wave-uniform
        f32x4 zero = {0.0f, 0.0f, 0.0f, 0.0f};
        f32x4 acc[4] = {zero, zero, zero, zero};
#pragma unroll
        for (int kt = 0; kt < 2; ++kt) {
            half8 av = *(const half8*)(act + (size_t)(n0 + m) * HID + kt * 32 + quad * 8);
#pragma unroll
            for (int j = 0; j < 8; ++j)
                av[j] = av[j] > (_Float16)0 ? av[j] : (_Float16)0;
#pragma unroll
            for (int c = 0; c < 4; ++c) {
                half8 bv = Wf8[(kt * 4 + c) * 64 + lane];
                acc[c] = __builtin_amdgcn_mfma_f32_16x16x32_f16(av, bv, acc[c], 0, 0, 0);
            }
        }
#pragma unroll
        for (int r = 0; r < 4; ++r) {
            int node = n0 + quad * 4 + r;
            if (node < a.N) {
                float dv = a.dinv[node];
#pragma unroll
                for (int c = 0; c < 4; ++c)
                    h[(size_t)node * HID + c * 16 + m] = __float2half(acc[c][r] * dv);
            }
        }
    }
}

// ===== P10: fused mean-pool + head (grid-stride over graphs) ==============
__device__ void phase10(const Args& a, SMem& sm) {
    const int t = threadIdx.x;
    for (int g = blockIdx.x; g < NGRAPHS; g += gridDim.x) {
        int lo = 0, hi = a.N;
        while (lo < hi) { int m = (lo + hi) >> 1; if (a.batch[m] < g) lo = m + 1; else hi = m; }
        int nstart = lo;
        hi = a.N;
        while (lo < hi) { int m = (lo + hi) >> 1; if (a.batch[m] < g + 1) lo = m + 1; else hi = m; }
        int nend = lo;

        int c = t & 63, part = t >> 6;
        float acc = 0.0f;
        for (int n = nstart + part; n < nend; n += 4)
            acc += __half2float(a.bufA[(size_t)n * HID + c]);

        __syncthreads();
        sm.p10.red[part][c] = acc;
        __syncthreads();
        if (t < 64) {
            float cntf = (float)(nend - nstart);
            float pooled = (sm.p10.red[0][c] + sm.p10.red[1][c] +
                            sm.p10.red[2][c] + sm.p10.red[3][c]) / fmaxf(cntf, 1.0f);
            sm.p10.hd[c] = pooled * a.Wl[c * 2 + 0];
            sm.p10.hd[64 + c] = pooled * a.Wl[c * 2 + 1];
        }
        __syncthreads();
        if (t < 2) {
            float s = 0.0f;
            for (int k = 0; k < 64; k++) s += sm.p10.hd[t * 64 + k];
            a.out[g * 2 + t] = s + a.bl[t];
        }
        __syncthreads();
    }
}

// ===== cooperative mega-kernel ============================================
__global__ __launch_bounds__(256) void k_mega(Args a) {
    cg::grid_group grid = cg::this_grid();
    __shared__ SMem sm;
    phase0(a, sm);  grid.sync();
    phase1(a, sm);  grid.sync();
    phase2(a, sm);  grid.sync();
    phase3(a, sm);  grid.sync();
    phase4(a, sm);  grid.sync();
    agg_phase(a, a.bufH, a.b1, a.bufA);   grid.sync();
    mfma_phase(a, a.bufA, a.Wf2, a.bufH); grid.sync();
    agg_phase(a, a.bufH, a.b2, a.bufA);   grid.sync();
    mfma_phase(a, a.bufA, a.Wf3, a.bufH); grid.sync();
    agg_phase(a, a.bufH, a.b3, a.bufA);   grid.sync();
    phase10(a, sm);
}

// ===== discrete fallback wrappers (identical math, R11 path) ==============
__global__ __launch_bounds__(256) void k_p0(Args a) { __shared__ SMem sm; phase0(a, sm); }
__global__ __launch_bounds__(256) void k_p1(Args a) { __shared__ SMem sm; phase1(a, sm); }
__global__ __launch_bounds__(256) void k_p2(Args a) { __shared__ SMem sm; phase2(a, sm); }
__global__ __launch_bounds__(256) void k_p3(Args a) { __shared__ SMem sm; phase3(a, sm); }
__global__ __launch_bounds__(256) void k_p4(Args a) { __shared__ SMem sm; phase4(a, sm); }
__global__ __launch_bounds__(256) void k_agg1(Args a) { agg_phase(a, a.bufH, a.b1, a.bufA); }
__global__ __launch_bounds__(256) void k_agg2(Args a) { agg_phase(a, a.bufH, a.b2, a.bufA); }
__global__ __launch_bounds__(256) void k_agg3(Args a) { agg_phase(a, a.bufH, a.b3, a.bufA); }
__global__ __launch_bounds__(256) void k_mfma2(Args a) { mfma_phase(a, a.bufA, a.Wf2, a.bufH); }
__global__ __launch_bounds__(256) void k_mfma3(Args a) { mfma_phase(a, a.bufA, a.Wf3, a.bufH); }
__global__ __launch_bounds__(256) void k_p10(Args a) { __shared__ SMem sm; phase10(a, sm); }

// -------------------------------------------------------------------------

extern "C" void kernel_launch(void* const* d_in, const int* in_sizes, int n_in,
                              void* d_out, int out_size, void* d_ws, size_t ws_size,
                              hipStream_t stream) {
    const int N = in_sizes[0] / 7;     // 100000
    const int E = in_sizes[1] / 2;     // 1250000

    Args a;
    a.x  = (const float*)d_in[0];
    const int* ei = (const int*)d_in[1];
    a.src = ei;
    a.dst = ei + E;
    a.batch = (const int*)d_in[2];
    a.W1 = (const float*)d_in[3];  a.b1 = (const float*)d_in[4];
    a.W2 = (const float*)d_in[5];  a.b2 = (const float*)d_in[6];
    a.W3 = (const float*)d_in[7];  a.b3 = (const float*)d_in[8];
    a.Wl = (const float*)d_in[9];  a.bl = (const float*)d_in[10];
    a.out = (float*)d_out;
    a.N = N; a.E = E;
    a.nbkt = (N + BKTSZ - 1) >> BKTSH;            // 196
    a.nchunk = (E + CHUNK - 1) / CHUNK;           // 153
    const int lenH = a.nbkt * a.nchunk;
    a.nscan = (lenH + 1023) / 1024;               // 30 (<=32 for bpref[])

    char* ws = (char*)d_ws;
    size_t off = 0;
    auto carve = [&](size_t bytes) {
        void* p = ws + off;
        off = (off + bytes + 255) & ~(size_t)255;
        return p;
    };
    a.H      = (int*)carve((size_t)lenH * 4);
    a.Hs     = (int*)carve((size_t)lenH * 4);
    a.bsum   = (int*)carve(512 * 4);
    a.packed = (int*)carve((size_t)E * 4);
    a.csr    = (int*)carve((size_t)E * 4);
    a.rowptr = (int*)carve((size_t)(N + 1) * 4);
    a.dinv   = (float*)carve((size_t)N * 4);
    a.Wf2    = (__half*)carve(4096 * 2);
    a.Wf3    = (__half*)carve(4096 * 2);
    a.bufH   = (__half*)carve((size_t)(N + 64) * HID * 2);   // +64 pad rows
    a.bufA   = (__half*)carve((size_t)(N + 64) * HID * 2);

    // ---- try cooperative path: size grid by MEASURED occupancy ----------
    int dev = 0;
    (void)hipGetDevice(&dev);
    int numCU = 0;
    (void)hipDeviceGetAttribute(&numCU, hipDeviceAttributeMultiprocessorCount, dev);
    int occ = 0;
    hipError_t eq = hipOccupancyMaxActiveBlocksPerMultiprocessor(
        &occ, (const void*)k_mega, 256, 0);
    if (eq == hipSuccess && occ >= 1 && numCU >= 1) {
        int grid = occ * numCU;
        if (grid > 2048) grid = 2048;
        void* params[] = { &a };
        hipError_t el = hipLaunchCooperativeKernel(
            (const void*)k_mega, dim3(grid), dim3(256), params, 0, stream);
        if (el == hipSuccess) return;
    }

    // ---- fallback: discrete launches (R11-equivalent) -------------------
    const int nb_work = 1024;
    k_p0<<<a.nchunk, 256, 0, stream>>>(a);
    k_p1<<<a.nscan, 256, 0, stream>>>(a);
    k_p2<<<a.nchunk, 256, 0, stream>>>(a);
    k_p3<<<a.nbkt, 256, 0, stream>>>(a);
    k_p4<<<nb_work, 256, 0, stream>>>(a);
    k_agg1<<<nb_work, 256, 0, stream>>>(a);
    k_mfma2<<<nb_work, 256, 0, stream>>>(a);
    k_agg2<<<nb_work, 256, 0, stream>>>(a);
    k_mfma3<<<nb_work, 256, 0, stream>>>(a);
    k_agg3<<<nb_work, 256, 0, stream>>>(a);
    k_p10<<<NGRAPHS, 256, 0, stream>>>(a);
}

// Round 14
// 301.716 us; speedup vs baseline: 3.1430x; 3.1430x over previous
//
#include <hip/hip_runtime.h>
#include <hip/hip_fp16.h>

#define HID 64
#define NGRAPHS 256
#define CHUNK 8192        // edges per pass-1 chunk
#define BKTSZ 512         // nodes per coarse bucket
#define BKTSH 9
#define PSH 17            // src fits in 17 bits (N <= 131072)
#define PMASK 0x1FFFF

typedef _Float16 half8 __attribute__((ext_vector_type(8)));
typedef float f32x4 __attribute__((ext_vector_type(4)));

// MEASURED LAWS (R1-R13):
//  - scattered device-scope atomics/stores write through ~64B lines at
//    ~0.9 TB/s, parallelism/padding-invariant -> LDS counting-sort CSR.
//  - grid.sync() cooperative barrier costs ~100us at full grid -> NEVER
//    use coop here; discrete launches (~6-7us/boundary) are cheaper.
//  - agg gather of fp16 128B rows runs near L2/L3 BW; fp16 h halves it.

// ---- P0: prepW (blocks 0-1) + per-chunk coarse histogram ----------------

__global__ __launch_bounds__(256) void k_hist(
        const int* __restrict__ dst, const float* __restrict__ W2,
        const float* __restrict__ W3, __half* __restrict__ Wf2,
        __half* __restrict__ Wf3, int* __restrict__ H,
        int e, int nbkt, int nchunk) {
    __shared__ int cnt[256];
    const int t = threadIdx.x, b = blockIdx.x;
    const int gtid = b * 256 + t;
    if (gtid < 512) {       // W fragment repack: 16x16x32-f16 B layout
        int p = gtid;
        int kt = p >> 8, c = (p >> 6) & 3, lane = p & 63;
        int quad = lane >> 4, m = lane & 15;
#pragma unroll
        for (int j = 0; j < 8; ++j) {
            int k = kt * 32 + quad * 8 + j;
            int ch = c * 16 + m;
            Wf2[(size_t)p * 8 + j] = __float2half(W2[k * HID + ch]);
            Wf3[(size_t)p * 8 + j] = __float2half(W3[k * HID + ch]);
        }
    }
    for (int i = t; i < nbkt; i += 256) cnt[i] = 0;
    __syncthreads();
#pragma unroll
    for (int it = 0; it < CHUNK / 1024; ++it) {
        int idx = b * CHUNK + it * 1024 + t * 4;
        if (idx + 3 < e) {
            int4 d = *(const int4*)(dst + idx);
            atomicAdd(&cnt[d.x >> BKTSH], 1);
            atomicAdd(&cnt[d.y >> BKTSH], 1);
            atomicAdd(&cnt[d.z >> BKTSH], 1);
            atomicAdd(&cnt[d.w >> BKTSH], 1);
        } else {
            for (int i = idx; i < e && i < idx + 4; ++i)
                atomicAdd(&cnt[dst[i] >> BKTSH], 1);
        }
    }
    __syncthreads();
    for (int i = t; i < nbkt; i += 256) H[i * nchunk + b] = cnt[i];
}

// ---- P1: per-1024 partial exclusive scans + block sums ------------------

__global__ __launch_bounds__(256) void k_scan(const int* __restrict__ in,
                                              int* __restrict__ outp,
                                              int* __restrict__ bsum, int n) {
    __shared__ int sh[256];
    const int t = threadIdx.x;
    const int base = blockIdx.x * 1024 + t * 4;
    int v[4];
    int s = 0;
#pragma unroll
    for (int k = 0; k < 4; k++) {
        int i = base + k;
        v[k] = (i < n) ? in[i] : 0;
        s += v[k];
    }
    sh[t] = s;
    __syncthreads();
#pragma unroll
    for (int off = 1; off < 256; off <<= 1) {
        int add = (t >= off) ? sh[t - off] : 0;
        __syncthreads();
        sh[t] += add;
        __syncthreads();
    }
    int run = sh[t] - s;
#pragma unroll
    for (int k = 0; k < 4; k++) {
        int i = base + k;
        if (i < n) outp[i] = run;
        run += v[k];
    }
    if (t == 255) bsum[blockIdx.x] = sh[255];
}

// ---- P2: bucket scatter (packed 4B, coalesced runs) ---------------------

__global__ __launch_bounds__(256) void k_scatter(
        const int* __restrict__ src, const int* __restrict__ dst,
        const int* __restrict__ Hs, const int* __restrict__ bsum,
        int* __restrict__ packed, int e, int nbkt, int nchunk, int nscan) {
    __shared__ int off[256];
    __shared__ int lc[256];
    __shared__ int bpref[32];
    const int t = threadIdx.x, b = blockIdx.x;
    if (t == 0) {
        int run = 0;
        for (int i = 0; i < nscan; ++i) { bpref[i] = run; run += bsum[i]; }
    }
    __syncthreads();
    for (int i = t; i < nbkt; i += 256) {
        int idx = i * nchunk + b;
        off[i] = Hs[idx] + bpref[idx >> 10];
        lc[i] = 0;
    }
    __syncthreads();
#pragma unroll
    for (int it = 0; it < CHUNK / 1024; ++it) {
        int idx = b * CHUNK + it * 1024 + t * 4;
        if (idx + 3 < e) {
            int4 d = *(const int4*)(dst + idx);
            int4 s = *(const int4*)(src + idx);
            int b0 = d.x >> BKTSH, b1 = d.y >> BKTSH;
            int b2 = d.z >> BKTSH, b3 = d.w >> BKTSH;
            int r0 = atomicAdd(&lc[b0], 1);
            int r1 = atomicAdd(&lc[b1], 1);
            int r2 = atomicAdd(&lc[b2], 1);
            int r3 = atomicAdd(&lc[b3], 1);
            packed[off[b0] + r0] = s.x | ((d.x & (BKTSZ - 1)) << PSH);
            packed[off[b1] + r1] = s.y | ((d.y & (BKTSZ - 1)) << PSH);
            packed[off[b2] + r2] = s.z | ((d.z & (BKTSZ - 1)) << PSH);
            packed[off[b3] + r3] = s.w | ((d.w & (BKTSZ - 1)) << PSH);
        } else {
            for (int i = idx; i < e && i < idx + 4; ++i) {
                int dd = dst[i];
                int bk = dd >> BKTSH;
                int r = atomicAdd(&lc[bk], 1);
                packed[off[bk] + r] = src[i] | ((dd & (BKTSZ - 1)) << PSH);
            }
        }
    }
}

// ---- P3: per-bucket local CSR build + FUSED layer-1 gemm ----------------
// Bucket block owns nodes [bkt*512, bkt*512+512): builds rowptr/dinv/csr
// from LDS counters, then computes h' = (x @ W1) * dinv for its own nodes
// (deg still in LDS -> no dinv round-trip, one less launch).

__global__ __launch_bounds__(256) void k_csr_gemm(
        const int* __restrict__ packed, const int* __restrict__ Hs,
        const int* __restrict__ bsum, const float* __restrict__ x,
        const float* __restrict__ W1, int* __restrict__ rowptr,
        float* __restrict__ dinv, int* __restrict__ csr,
        __half* __restrict__ h, int e, int n, int nbkt, int nchunk, int nscan) {
    __shared__ int cnt[BKTSZ];
    __shared__ int pref[BKTSZ];
    __shared__ int ssum[256];
    __shared__ int cnt2[BKTSZ];
    __shared__ int bpref[32];
    __shared__ float Wsh[7 * HID];
    __shared__ float Ash[16 * 7];
    const int t = threadIdx.x, bkt = blockIdx.x;
    if (t == 0) {
        int run = 0;
        for (int i = 0; i < nscan; ++i) { bpref[i] = run; run += bsum[i]; }
    }
    if (bkt == 0 && t == 0) rowptr[n] = e;
    for (int i = t; i < 7 * HID; i += 256) Wsh[i] = W1[i];
    cnt[t] = 0; cnt[t + 256] = 0;
    cnt2[t] = 0; cnt2[t + 256] = 0;
    __syncthreads();
    int i0 = bkt * nchunk;
    int segStart = Hs[i0] + bpref[i0 >> 10];
    int segEnd = e;
    if (bkt + 1 < nbkt) {
        int i1 = (bkt + 1) * nchunk;
        segEnd = Hs[i1] + bpref[i1 >> 10];
    }
    for (int j = segStart + t; j < segEnd; j += 256)
        atomicAdd(&cnt[(packed[j] >> PSH) & (BKTSZ - 1)], 1);
    __syncthreads();
    int a0 = cnt[2 * t], a1 = cnt[2 * t + 1];
    int s = a0 + a1;
    ssum[t] = s;
    __syncthreads();
#pragma unroll
    for (int off = 1; off < 256; off <<= 1) {
        int add = (t >= off) ? ssum[t - off] : 0;
        __syncthreads();
        ssum[t] += add;
        __syncthreads();
    }
    int p = ssum[t] - s;
    pref[2 * t] = p;
    pref[2 * t + 1] = p + a0;
    __syncthreads();
    for (int i = t; i < BKTSZ; i += 256) {
        int node = bkt * BKTSZ + i;
        if (node < n) {
            rowptr[node] = segStart + pref[i];
            dinv[node] = rsqrtf((float)(cnt[i] + 1));   // +1 self-loop
        }
    }
    for (int j = segStart + t; j < segEnd; j += 256) {
        int pk = packed[j];
        int ld = (pk >> PSH) & (BKTSZ - 1);
        int r = atomicAdd(&cnt2[ld], 1);
        csr[segStart + pref[ld] + r] = pk & PMASK;
    }
    // ---- fused gemm7 for this bucket's nodes (deg in cnt[]) ----
    const int c = t & 63;
    const int g = t >> 6;
    for (int chunk = 0; chunk < BKTSZ / 16; ++chunk) {
        int n0 = bkt * BKTSZ + chunk * 16;
        if (n0 >= n) break;
        const long long lim = (long long)(n - n0) * 7;
        __syncthreads();
        for (int i = t; i < 16 * 7; i += 256)
            Ash[i] = (i < lim) ? x[(size_t)n0 * 7 + i] : 0.0f;
        __syncthreads();
        float acc[4] = {0.0f, 0.0f, 0.0f, 0.0f};
#pragma unroll
        for (int k = 0; k < 7; k++) {
            float w = Wsh[k * HID + c];
#pragma unroll
            for (int i = 0; i < 4; i++) acc[i] += Ash[(g * 4 + i) * 7 + k] * w;
        }
#pragma unroll
        for (int i = 0; i < 4; i++) {
            int nn = n0 + g * 4 + i;
            if (nn < n) {
                int loc = nn - bkt * BKTSZ;
                float dv = rsqrtf((float)(cnt[loc] + 1));
                h[(size_t)nn * HID + c] = __float2half(acc[i] * dv);
            }
        }
    }
}

// ---- CSR aggregate: weightless, 16/8/4-wide, fp16 in/out ----------------
// agg = b + dv*(h'[d] + sum h'[s]); fp32 accumulation.

__device__ __forceinline__ float4 h4_to_f4(int2 raw) {
    __half2 p0 = *(__half2*)&raw.x;
    __half2 p1 = *(__half2*)&raw.y;
    float2 f0 = __half22float2(p0);
    float2 f1 = __half22float2(p1);
    return make_float4(f0.x, f0.y, f1.x, f1.y);
}

__global__ __launch_bounds__(256) void k_aggregate(
        const int* __restrict__ rowptr, const int* __restrict__ csr,
        const __half* __restrict__ h, const float* __restrict__ b,
        const float* __restrict__ dinv, __half* __restrict__ agg, int n_nodes) {
    int node = blockIdx.x * 16 + (threadIdx.x >> 4);
    int l16 = threadIdx.x & 15;
    if (node >= n_nodes) return;
    int beg = rowptr[node], end = rowptr[node + 1];
    const int2* h8 = (const int2*)h;
    const float4* b4 = (const float4*)b;
    float dv = dinv[node];
    float4 inner = h4_to_f4(h8[(size_t)node * 16 + l16]);   // self h'
    int j = beg;
    for (; j + 15 < end; j += 16) {               // 16 outstanding gathers
        int s[16];
#pragma unroll
        for (int q = 0; q < 16; ++q) s[q] = csr[j + q];
        int2 r[16];
#pragma unroll
        for (int q = 0; q < 16; ++q) r[q] = h8[(size_t)s[q] * 16 + l16];
#pragma unroll
        for (int q = 0; q < 16; ++q) {
            float4 v = h4_to_f4(r[q]);
            inner.x += v.x; inner.y += v.y; inner.z += v.z; inner.w += v.w;
        }
    }
    for (; j + 7 < end; j += 8) {
        int s[8];
#pragma unroll
        for (int q = 0; q < 8; ++q) s[q] = csr[j + q];
        int2 r[8];
#pragma unroll
        for (int q = 0; q < 8; ++q) r[q] = h8[(size_t)s[q] * 16 + l16];
#pragma unroll
        for (int q = 0; q < 8; ++q) {
            float4 v = h4_to_f4(r[q]);
            inner.x += v.x; inner.y += v.y; inner.z += v.z; inner.w += v.w;
        }
    }
    for (; j + 3 < end; j += 4) {
        int s0 = csr[j], s1 = csr[j + 1], s2 = csr[j + 2], s3 = csr[j + 3];
        float4 v0 = h4_to_f4(h8[(size_t)s0 * 16 + l16]);
        float4 v1 = h4_to_f4(h8[(size_t)s1 * 16 + l16]);
        float4 v2 = h4_to_f4(h8[(size_t)s2 * 16 + l16]);
        float4 v3 = h4_to_f4(h8[(size_t)s3 * 16 + l16]);
        inner.x += v0.x + v1.x + v2.x + v3.x;
        inner.y += v0.y + v1.y + v2.y + v3.y;
        inner.z += v0.z + v1.z + v2.z + v3.z;
        inner.w += v0.w + v1.w + v2.w + v3.w;
    }
    for (; j < end; j++) {
        float4 v = h4_to_f4(h8[(size_t)csr[j] * 16 + l16]);
        inner.x += v.x; inner.y += v.y; inner.z += v.z; inner.w += v.w;
    }
    float4 bb = b4[l16];
    __half2 q0 = __floats2half2_rn(bb.x + dv * inner.x, bb.y + dv * inner.y);
    __half2 q1 = __floats2half2_rn(bb.z + dv * inner.z, bb.w + dv * inner.w);
    int2 outv;
    outv.x = *(int*)&q0;
    outv.y = *(int*)&q1;
    ((int2*)agg)[(size_t)node * 16 + l16] = outv;
}

// ---- layers 2/3: MFMA gemm, no LDS: h' = (relu(act) @ W) * dinv ---------
// A-frag: lane holds act[n0+(lane&15)][kt*32+(lane>>4)*8+j] (16B load).
// D: col=lane&15 (ch), row=(lane>>4)*4+reg (node). [verified R10/R11]

__global__ __launch_bounds__(256) void k_gemm_mfma(
        const __half* __restrict__ act, const __half* __restrict__ Wf,
        const float* __restrict__ dinv, __half* __restrict__ h, int n_nodes) {
    const int wave = threadIdx.x >> 6;
    const int lane = threadIdx.x & 63;
    const int quad = lane >> 4, m = lane & 15;
    const int n0 = blockIdx.x * 64 + wave * 16;
    if (n0 >= n_nodes) return;            // wave-uniform
    const half8* Wf8 = (const half8*)Wf;
    f32x4 zero = {0.0f, 0.0f, 0.0f, 0.0f};
    f32x4 acc[4] = {zero, zero, zero, zero};
#pragma unroll
    for (int kt = 0; kt < 2; ++kt) {
        half8 av = *(const half8*)(act + (size_t)(n0 + m) * HID + kt * 32 + quad * 8);
#pragma unroll
        for (int j = 0; j < 8; ++j)
            av[j] = av[j] > (_Float16)0 ? av[j] : (_Float16)0;
#pragma unroll
        for (int c = 0; c < 4; ++c) {
            half8 bv = Wf8[(kt * 4 + c) * 64 + lane];
            acc[c] = __builtin_amdgcn_mfma_f32_16x16x32_f16(av, bv, acc[c], 0, 0, 0);
        }
    }
#pragma unroll
    for (int r = 0; r < 4; ++r) {
        int node = n0 + quad * 4 + r;
        if (node < n_nodes) {
            float dv = dinv[node];
#pragma unroll
            for (int c = 0; c < 4; ++c)
                h[(size_t)node * HID + c * 16 + m] = __float2half(acc[c][r] * dv);
        }
    }
}

// ---- fused mean-pool + head: one block per graph, batch sorted ----------

__global__ __launch_bounds__(256) void k_pool_head(
        const __half* __restrict__ agg, const int* __restrict__ batch,
        const float* __restrict__ Wl, const float* __restrict__ bl,
        float* __restrict__ out, int n_nodes) {
    int g = blockIdx.x;
    int lo = 0, hi = n_nodes;
    while (lo < hi) { int m = (lo + hi) >> 1; if (batch[m] < g) lo = m + 1; else hi = m; }
    int nstart = lo;
    hi = n_nodes;
    while (lo < hi) { int m = (lo + hi) >> 1; if (batch[m] < g + 1) lo = m + 1; else hi = m; }
    int nend = lo;

    int c = threadIdx.x & 63, part = threadIdx.x >> 6;
    float acc = 0.0f;
    for (int n = nstart + part; n < nend; n += 4)
        acc += __half2float(agg[(size_t)n * HID + c]);

    __shared__ float red[4][64];
    __shared__ float hd[128];
    red[part][c] = acc;
    __syncthreads();
    if (threadIdx.x < 64) {
        float cntf = (float)(nend - nstart);
        float pooled = (red[0][c] + red[1][c] + red[2][c] + red[3][c])
                       / fmaxf(cntf, 1.0f);
        hd[c] = pooled * Wl[c * 2 + 0];
        hd[64 + c] = pooled * Wl[c * 2 + 1];
    }
    __syncthreads();
    if (threadIdx.x < 2) {
        float s = 0.0f;
        for (int k = 0; k < 64; k++) s += hd[threadIdx.x * 64 + k];
        out[g * 2 + threadIdx.x] = s + bl[threadIdx.x];
    }
}

// -------------------------------------------------------------------------

extern "C" void kernel_launch(void* const* d_in, const int* in_sizes, int n_in,
                              void* d_out, int out_size, void* d_ws, size_t ws_size,
                              hipStream_t stream) {
    const float* x     = (const float*)d_in[0];
    const int*   ei    = (const int*)d_in[1];
    const int*   batch = (const int*)d_in[2];
    const float* W1    = (const float*)d_in[3];
    const float* b1    = (const float*)d_in[4];
    const float* W2    = (const float*)d_in[5];
    const float* b2    = (const float*)d_in[6];
    const float* W3    = (const float*)d_in[7];
    const float* b3    = (const float*)d_in[8];
    const float* Wl    = (const float*)d_in[9];
    const float* bl    = (const float*)d_in[10];
    float* out = (float*)d_out;

    const int N = in_sizes[0] / 7;     // 100000
    const int E = in_sizes[1] / 2;     // 1250000
    const int* src = ei;
    const int* dst = ei + E;

    const int nbkt   = (N + BKTSZ - 1) >> BKTSH;          // 196
    const int nchunk = (E + CHUNK - 1) / CHUNK;           // 153
    const int lenH   = nbkt * nchunk;
    const int nscan  = (lenH + 1023) / 1024;              // 30 (<=32)

    char* ws = (char*)d_ws;
    size_t off = 0;
    auto carve = [&](size_t bytes) {
        void* p = ws + off;
        off = (off + bytes + 255) & ~(size_t)255;
        return p;
    };
    int*    H      = (int*)carve((size_t)lenH * 4);
    int*    Hs     = (int*)carve((size_t)lenH * 4);
    int*    bsum   = (int*)carve(512 * 4);
    int*    packed = (int*)carve((size_t)E * 4);
    int*    csr    = (int*)carve((size_t)E * 4);
    int*    rowptr = (int*)carve((size_t)(N + 1) * 4);
    float*  dinv   = (float*)carve((size_t)N * 4);
    __half* Wf2    = (__half*)carve(4096 * 2);
    __half* Wf3    = (__half*)carve(4096 * 2);
    __half* bufH   = (__half*)carve((size_t)(N + 64) * HID * 2);  // +pad rows
    __half* bufA   = (__half*)carve((size_t)(N + 64) * HID * 2);

    const int nb_agg  = (N + 15) / 16;     // 6250
    const int nb_mfma = (N + 63) / 64;     // 1563

    // ---- CSR build (LDS counting sort) + fused layer-1 gemm
    k_hist<<<nchunk, 256, 0, stream>>>(dst, W2, W3, Wf2, Wf3, H, E, nbkt, nchunk);
    k_scan<<<nscan, 256, 0, stream>>>(H, Hs, bsum, lenH);
    k_scatter<<<nchunk, 256, 0, stream>>>(src, dst, Hs, bsum, packed,
                                          E, nbkt, nchunk, nscan);
    k_csr_gemm<<<nbkt, 256, 0, stream>>>(packed, Hs, bsum, x, W1, rowptr,
                                         dinv, csr, bufH, E, N, nbkt, nchunk, nscan);

    // ---- layer 1 aggregate; layers 2/3 MFMA gemm + aggregate
    k_aggregate<<<nb_agg, 256, 0, stream>>>(rowptr, csr, bufH, b1, dinv, bufA, N);
    k_gemm_mfma<<<nb_mfma, 256, 0, stream>>>(bufA, Wf2, dinv, bufH, N);
    k_aggregate<<<nb_agg, 256, 0, stream>>>(rowptr, csr, bufH, b2, dinv, bufA, N);
    k_gemm_mfma<<<nb_mfma, 256, 0, stream>>>(bufA, Wf3, dinv, bufH, N);
    k_aggregate<<<nb_agg, 256, 0, stream>>>(rowptr, csr, bufH, b3, dinv, bufA, N);

    // ---- fused mean-pool + head (one block per graph)
    k_pool_head<<<NGRAPHS, 256, 0, stream>>>(bufA, batch, Wl, bl, out, N);
}

// Round 15
// 287.395 us; speedup vs baseline: 3.2996x; 1.0498x over previous
//
#include <hip/hip_runtime.h>
#include <hip/hip_fp16.h>

#define HID 64
#define NGRAPHS 256
#define CHUNK 8192        // edges per pass-1 chunk
#define BKTSZ 512         // nodes per coarse bucket
#define BKTSH 9
#define PSH 17            // src fits in 17 bits (N <= 131072)
#define PMASK 0x1FFFF

typedef _Float16 half8 __attribute__((ext_vector_type(8)));
typedef float f32x4 __attribute__((ext_vector_type(4)));

// MEASURED LAWS (R1-R14):
//  - scattered device-scope atomics/stores write through ~64B lines at
//    ~0.9 TB/s, parallelism/padding-invariant -> LDS counting-sort CSR.
//  - grid.sync() coop barrier ~100us at full grid (R13: 948us total) ->
//    discrete launches (~6-7us/boundary) are strictly cheaper here.
//  - R14: fusing the wide gemm7 into the 196-block csr_build serialized
//    it (6.6% occupancy, +30us) -> keep wide phases on wide grids.

// ---- P0: prepW (blocks 0-1) + per-chunk coarse histogram ----------------

__global__ __launch_bounds__(256) void k_hist(
        const int* __restrict__ dst, const float* __restrict__ W2,
        const float* __restrict__ W3, __half* __restrict__ Wf2,
        __half* __restrict__ Wf3, int* __restrict__ H,
        int e, int nbkt, int nchunk) {
    __shared__ int cnt[256];
    const int t = threadIdx.x, b = blockIdx.x;
    const int gtid = b * 256 + t;
    if (gtid < 512) {       // W fragment repack: 16x16x32-f16 B layout
        int p = gtid;
        int kt = p >> 8, c = (p >> 6) & 3, lane = p & 63;
        int quad = lane >> 4, m = lane & 15;
#pragma unroll
        for (int j = 0; j < 8; ++j) {
            int k = kt * 32 + quad * 8 + j;
            int ch = c * 16 + m;
            Wf2[(size_t)p * 8 + j] = __float2half(W2[k * HID + ch]);
            Wf3[(size_t)p * 8 + j] = __float2half(W3[k * HID + ch]);
        }
    }
    for (int i = t; i < nbkt; i += 256) cnt[i] = 0;
    __syncthreads();
#pragma unroll
    for (int it = 0; it < CHUNK / 1024; ++it) {
        int idx = b * CHUNK + it * 1024 + t * 4;
        if (idx + 3 < e) {
            int4 d = *(const int4*)(dst + idx);
            atomicAdd(&cnt[d.x >> BKTSH], 1);
            atomicAdd(&cnt[d.y >> BKTSH], 1);
            atomicAdd(&cnt[d.z >> BKTSH], 1);
            atomicAdd(&cnt[d.w >> BKTSH], 1);
        } else {
            for (int i = idx; i < e && i < idx + 4; ++i)
                atomicAdd(&cnt[dst[i] >> BKTSH], 1);
        }
    }
    __syncthreads();
    for (int i = t; i < nbkt; i += 256) H[i * nchunk + b] = cnt[i];
}

// ---- P1: per-1024 partial exclusive scans + block sums ------------------

__global__ __launch_bounds__(256) void k_scan(const int* __restrict__ in,
                                              int* __restrict__ outp,
                                              int* __restrict__ bsum, int n) {
    __shared__ int sh[256];
    const int t = threadIdx.x;
    const int base = blockIdx.x * 1024 + t * 4;
    int v[4];
    int s = 0;
#pragma unroll
    for (int k = 0; k < 4; k++) {
        int i = base + k;
        v[k] = (i < n) ? in[i] : 0;
        s += v[k];
    }
    sh[t] = s;
    __syncthreads();
#pragma unroll
    for (int off = 1; off < 256; off <<= 1) {
        int add = (t >= off) ? sh[t - off] : 0;
        __syncthreads();
        sh[t] += add;
        __syncthreads();
    }
    int run = sh[t] - s;
#pragma unroll
    for (int k = 0; k < 4; k++) {
        int i = base + k;
        if (i < n) outp[i] = run;
        run += v[k];
    }
    if (t == 255) bsum[blockIdx.x] = sh[255];
}

// ---- P2: bucket scatter (packed 4B, coalesced runs) ---------------------

__global__ __launch_bounds__(256) void k_scatter(
        const int* __restrict__ src, const int* __restrict__ dst,
        const int* __restrict__ Hs, const int* __restrict__ bsum,
        int* __restrict__ packed, int e, int nbkt, int nchunk, int nscan) {
    __shared__ int off[256];
    __shared__ int lc[256];
    __shared__ int bpref[32];
    const int t = threadIdx.x, b = blockIdx.x;
    if (t == 0) {
        int run = 0;
        for (int i = 0; i < nscan; ++i) { bpref[i] = run; run += bsum[i]; }
    }
    __syncthreads();
    for (int i = t; i < nbkt; i += 256) {
        int idx = i * nchunk + b;
        off[i] = Hs[idx] + bpref[idx >> 10];
        lc[i] = 0;
    }
    __syncthreads();
#pragma unroll
    for (int it = 0; it < CHUNK / 1024; ++it) {
        int idx = b * CHUNK + it * 1024 + t * 4;
        if (idx + 3 < e) {
            int4 d = *(const int4*)(dst + idx);
            int4 s = *(const int4*)(src + idx);
            int b0 = d.x >> BKTSH, b1 = d.y >> BKTSH;
            int b2 = d.z >> BKTSH, b3 = d.w >> BKTSH;
            int r0 = atomicAdd(&lc[b0], 1);
            int r1 = atomicAdd(&lc[b1], 1);
            int r2 = atomicAdd(&lc[b2], 1);
            int r3 = atomicAdd(&lc[b3], 1);
            packed[off[b0] + r0] = s.x | ((d.x & (BKTSZ - 1)) << PSH);
            packed[off[b1] + r1] = s.y | ((d.y & (BKTSZ - 1)) << PSH);
            packed[off[b2] + r2] = s.z | ((d.z & (BKTSZ - 1)) << PSH);
            packed[off[b3] + r3] = s.w | ((d.w & (BKTSZ - 1)) << PSH);
        } else {
            for (int i = idx; i < e && i < idx + 4; ++i) {
                int dd = dst[i];
                int bk = dd >> BKTSH;
                int r = atomicAdd(&lc[bk], 1);
                packed[off[bk] + r] = src[i] | ((dd & (BKTSZ - 1)) << PSH);
            }
        }
    }
}

// ---- P3: per-bucket local CSR build (196 blocks, CSR work ONLY) ---------

__global__ __launch_bounds__(256) void k_csr_build(
        const int* __restrict__ packed, const int* __restrict__ Hs,
        const int* __restrict__ bsum, int* __restrict__ rowptr,
        float* __restrict__ dinv, int* __restrict__ csr,
        int e, int n, int nbkt, int nchunk, int nscan) {
    __shared__ int cnt[BKTSZ];
    __shared__ int pref[BKTSZ];
    __shared__ int ssum[256];
    __shared__ int cnt2[BKTSZ];
    __shared__ int bpref[32];
    const int t = threadIdx.x, bkt = blockIdx.x;
    if (t == 0) {
        int run = 0;
        for (int i = 0; i < nscan; ++i) { bpref[i] = run; run += bsum[i]; }
    }
    if (bkt == 0 && t == 0) rowptr[n] = e;
    cnt[t] = 0; cnt[t + 256] = 0;
    cnt2[t] = 0; cnt2[t + 256] = 0;
    __syncthreads();
    int i0 = bkt * nchunk;
    int segStart = Hs[i0] + bpref[i0 >> 10];
    int segEnd = e;
    if (bkt + 1 < nbkt) {
        int i1 = (bkt + 1) * nchunk;
        segEnd = Hs[i1] + bpref[i1 >> 10];
    }
    for (int j = segStart + t; j < segEnd; j += 256)
        atomicAdd(&cnt[(packed[j] >> PSH) & (BKTSZ - 1)], 1);
    __syncthreads();
    int a0 = cnt[2 * t], a1 = cnt[2 * t + 1];
    int s = a0 + a1;
    ssum[t] = s;
    __syncthreads();
#pragma unroll
    for (int off = 1; off < 256; off <<= 1) {
        int add = (t >= off) ? ssum[t - off] : 0;
        __syncthreads();
        ssum[t] += add;
        __syncthreads();
    }
    int p = ssum[t] - s;
    pref[2 * t] = p;
    pref[2 * t + 1] = p + a0;
    __syncthreads();
    for (int i = t; i < BKTSZ; i += 256) {
        int node = bkt * BKTSZ + i;
        if (node < n) {
            rowptr[node] = segStart + pref[i];
            dinv[node] = rsqrtf((float)(cnt[i] + 1));   // +1 self-loop
        }
    }
    for (int j = segStart + t; j < segEnd; j += 256) {
        int pk = packed[j];
        int ld = (pk >> PSH) & (BKTSZ - 1);
        int r = atomicAdd(&cnt2[ld], 1);
        csr[segStart + pref[ld] + r] = pk & PMASK;
    }
}

// ---- layer-1 gemm (K=7, fp32 in, WIDE grid): h' = (x @ W1) * dinv -------

__global__ __launch_bounds__(256) void k_gemm7(
        const float* __restrict__ act, const float* __restrict__ W,
        const float* __restrict__ dinv, __half* __restrict__ h, int n_nodes) {
    __shared__ float Wsh[7 * HID];
    __shared__ float Ash[16 * 7];
    const int t = threadIdx.x;
    const int n0 = blockIdx.x * 16;

    for (int i = t; i < 7 * HID; i += 256) Wsh[i] = W[i];
    const long long lim = (long long)(n_nodes - n0) * 7;
    for (int i = t; i < 16 * 7; i += 256)
        Ash[i] = (i < lim) ? act[(size_t)n0 * 7 + i] : 0.0f;
    __syncthreads();

    const int c = t & 63;
    const int g = t >> 6;
    float acc[4] = {0.0f, 0.0f, 0.0f, 0.0f};
#pragma unroll
    for (int k = 0; k < 7; k++) {
        float w = Wsh[k * HID + c];
#pragma unroll
        for (int i = 0; i < 4; i++) acc[i] += Ash[(g * 4 + i) * 7 + k] * w;
    }
#pragma unroll
    for (int i = 0; i < 4; i++) {
        int n = n0 + g * 4 + i;
        if (n < n_nodes) h[(size_t)n * HID + c] = __float2half(acc[i] * dinv[n]);
    }
}

// ---- CSR aggregate: weightless, 16/8/4-wide, fp16 in/out ----------------
// agg = b + dv*(h'[d] + sum h'[s]); fp32 accumulation.

__device__ __forceinline__ float4 h4_to_f4(int2 raw) {
    __half2 p0 = *(__half2*)&raw.x;
    __half2 p1 = *(__half2*)&raw.y;
    float2 f0 = __half22float2(p0);
    float2 f1 = __half22float2(p1);
    return make_float4(f0.x, f0.y, f1.x, f1.y);
}

__global__ __launch_bounds__(256) void k_aggregate(
        const int* __restrict__ rowptr, const int* __restrict__ csr,
        const __half* __restrict__ h, const float* __restrict__ b,
        const float* __restrict__ dinv, __half* __restrict__ agg, int n_nodes) {
    int node = blockIdx.x * 16 + (threadIdx.x >> 4);
    int l16 = threadIdx.x & 15;
    if (node >= n_nodes) return;
    int beg = rowptr[node], end = rowptr[node + 1];
    const int2* h8 = (const int2*)h;
    const float4* b4 = (const float4*)b;
    float dv = dinv[node];
    float4 inner = h4_to_f4(h8[(size_t)node * 16 + l16]);   // self h'
    int j = beg;
    for (; j + 15 < end; j += 16) {               // 16 outstanding gathers
        int s[16];
#pragma unroll
        for (int q = 0; q < 16; ++q) s[q] = csr[j + q];
        int2 r[16];
#pragma unroll
        for (int q = 0; q < 16; ++q) r[q] = h8[(size_t)s[q] * 16 + l16];
#pragma unroll
        for (int q = 0; q < 16; ++q) {
            float4 v = h4_to_f4(r[q]);
            inner.x += v.x; inner.y += v.y; inner.z += v.z; inner.w += v.w;
        }
    }
    for (; j + 7 < end; j += 8) {
        int s[8];
#pragma unroll
        for (int q = 0; q < 8; ++q) s[q] = csr[j + q];
        int2 r[8];
#pragma unroll
        for (int q = 0; q < 8; ++q) r[q] = h8[(size_t)s[q] * 16 + l16];
#pragma unroll
        for (int q = 0; q < 8; ++q) {
            float4 v = h4_to_f4(r[q]);
            inner.x += v.x; inner.y += v.y; inner.z += v.z; inner.w += v.w;
        }
    }
    for (; j + 3 < end; j += 4) {
        int s0 = csr[j], s1 = csr[j + 1], s2 = csr[j + 2], s3 = csr[j + 3];
        float4 v0 = h4_to_f4(h8[(size_t)s0 * 16 + l16]);
        float4 v1 = h4_to_f4(h8[(size_t)s1 * 16 + l16]);
        float4 v2 = h4_to_f4(h8[(size_t)s2 * 16 + l16]);
        float4 v3 = h4_to_f4(h8[(size_t)s3 * 16 + l16]);
        inner.x += v0.x + v1.x + v2.x + v3.x;
        inner.y += v0.y + v1.y + v2.y + v3.y;
        inner.z += v0.z + v1.z + v2.z + v3.z;
        inner.w += v0.w + v1.w + v2.w + v3.w;
    }
    for (; j < end; j++) {
        float4 v = h4_to_f4(h8[(size_t)csr[j] * 16 + l16]);
        inner.x += v.x; inner.y += v.y; inner.z += v.z; inner.w += v.w;
    }
    float4 bb = b4[l16];
    __half2 q0 = __floats2half2_rn(bb.x + dv * inner.x, bb.y + dv * inner.y);
    __half2 q1 = __floats2half2_rn(bb.z + dv * inner.z, bb.w + dv * inner.w);
    int2 outv;
    outv.x = *(int*)&q0;
    outv.y = *(int*)&q1;
    ((int2*)agg)[(size_t)node * 16 + l16] = outv;
}

// ---- layers 2/3: MFMA gemm, no LDS: h' = (relu(act) @ W) * dinv ---------
// A-frag: lane holds act[n0+(lane&15)][kt*32+(lane>>4)*8+j] (16B load).
// D: col=lane&15 (ch), row=(lane>>4)*4+reg (node). [verified R10/R11]

__global__ __launch_bounds__(256) void k_gemm_mfma(
        const __half* __restrict__ act, const __half* __restrict__ Wf,
        const float* __restrict__ dinv, __half* __restrict__ h, int n_nodes) {
    const int wave = threadIdx.x >> 6;
    const int lane = threadIdx.x & 63;
    const int quad = lane >> 4, m = lane & 15;
    const int n0 = blockIdx.x * 64 + wave * 16;
    if (n0 >= n_nodes) return;            // wave-uniform
    const half8* Wf8 = (const half8*)Wf;
    f32x4 zero = {0.0f, 0.0f, 0.0f, 0.0f};
    f32x4 acc[4] = {zero, zero, zero, zero};
#pragma unroll
    for (int kt = 0; kt < 2; ++kt) {
        half8 av = *(const half8*)(act + (size_t)(n0 + m) * HID + kt * 32 + quad * 8);
#pragma unroll
        for (int j = 0; j < 8; ++j)
            av[j] = av[j] > (_Float16)0 ? av[j] : (_Float16)0;
#pragma unroll
        for (int c = 0; c < 4; ++c) {
            half8 bv = Wf8[(kt * 4 + c) * 64 + lane];
            acc[c] = __builtin_amdgcn_mfma_f32_16x16x32_f16(av, bv, acc[c], 0, 0, 0);
        }
    }
#pragma unroll
    for (int r = 0; r < 4; ++r) {
        int node = n0 + quad * 4 + r;
        if (node < n_nodes) {
            float dv = dinv[node];
#pragma unroll
            for (int c = 0; c < 4; ++c)
                h[(size_t)node * HID + c * 16 + m] = __float2half(acc[c][r] * dv);
        }
    }
}

// ---- fused mean-pool + head: one block per graph, batch sorted ----------

__global__ __launch_bounds__(256) void k_pool_head(
        const __half* __restrict__ agg, const int* __restrict__ batch,
        const float* __restrict__ Wl, const float* __restrict__ bl,
        float* __restrict__ out, int n_nodes) {
    int g = blockIdx.x;
    int lo = 0, hi = n_nodes;
    while (lo < hi) { int m = (lo + hi) >> 1; if (batch[m] < g) lo = m + 1; else hi = m; }
    int nstart = lo;
    hi = n_nodes;
    while (lo < hi) { int m = (lo + hi) >> 1; if (batch[m] < g + 1) lo = m + 1; else hi = m; }
    int nend = lo;

    int c = threadIdx.x & 63, part = threadIdx.x >> 6;
    float acc = 0.0f;
    for (int n = nstart + part; n < nend; n += 4)
        acc += __half2float(agg[(size_t)n * HID + c]);

    __shared__ float red[4][64];
    __shared__ float hd[128];
    red[part][c] = acc;
    __syncthreads();
    if (threadIdx.x < 64) {
        float cntf = (float)(nend - nstart);
        float pooled = (red[0][c] + red[1][c] + red[2][c] + red[3][c])
                       / fmaxf(cntf, 1.0f);
        hd[c] = pooled * Wl[c * 2 + 0];
        hd[64 + c] = pooled * Wl[c * 2 + 1];
    }
    __syncthreads();
    if (threadIdx.x < 2) {
        float s = 0.0f;
        for (int k = 0; k < 64; k++) s += hd[threadIdx.x * 64 + k];
        out[g * 2 + threadIdx.x] = s + bl[threadIdx.x];
    }
}

// -------------------------------------------------------------------------

extern "C" void kernel_launch(void* const* d_in, const int* in_sizes, int n_in,
                              void* d_out, int out_size, void* d_ws, size_t ws_size,
                              hipStream_t stream) {
    const float* x     = (const float*)d_in[0];
    const int*   ei    = (const int*)d_in[1];
    const int*   batch = (const int*)d_in[2];
    const float* W1    = (const float*)d_in[3];
    const float* b1    = (const float*)d_in[4];
    const float* W2    = (const float*)d_in[5];
    const float* b2    = (const float*)d_in[6];
    const float* W3    = (const float*)d_in[7];
    const float* b3    = (const float*)d_in[8];
    const float* Wl    = (const float*)d_in[9];
    const float* bl    = (const float*)d_in[10];
    float* out = (float*)d_out;

    const int N = in_sizes[0] / 7;     // 100000
    const int E = in_sizes[1] / 2;     // 1250000
    const int* src = ei;
    const int* dst = ei + E;

    const int nbkt   = (N + BKTSZ - 1) >> BKTSH;          // 196
    const int nchunk = (E + CHUNK - 1) / CHUNK;           // 153
    const int lenH   = nbkt * nchunk;
    const int nscan  = (lenH + 1023) / 1024;              // 30 (<=32)

    char* ws = (char*)d_ws;
    size_t off = 0;
    auto carve = [&](size_t bytes) {
        void* p = ws + off;
        off = (off + bytes + 255) & ~(size_t)255;
        return p;
    };
    int*    H      = (int*)carve((size_t)lenH * 4);
    int*    Hs     = (int*)carve((size_t)lenH * 4);
    int*    bsum   = (int*)carve(512 * 4);
    int*    packed = (int*)carve((size_t)E * 4);
    int*    csr    = (int*)carve((size_t)E * 4);
    int*    rowptr = (int*)carve((size_t)(N + 1) * 4);
    float*  dinv   = (float*)carve((size_t)N * 4);
    __half* Wf2    = (__half*)carve(4096 * 2);
    __half* Wf3    = (__half*)carve(4096 * 2);
    __half* bufH   = (__half*)carve((size_t)(N + 64) * HID * 2);  // +pad rows
    __half* bufA   = (__half*)carve((size_t)(N + 64) * HID * 2);

    const int nb_gemm7 = (N + 15) / 16;    // 6250
    const int nb_agg   = (N + 15) / 16;    // 6250
    const int nb_mfma  = (N + 63) / 64;    // 1563

    // ---- CSR build (LDS counting sort)
    k_hist<<<nchunk, 256, 0, stream>>>(dst, W2, W3, Wf2, Wf3, H, E, nbkt, nchunk);
    k_scan<<<nscan, 256, 0, stream>>>(H, Hs, bsum, lenH);
    k_scatter<<<nchunk, 256, 0, stream>>>(src, dst, Hs, bsum, packed,
                                          E, nbkt, nchunk, nscan);
    k_csr_build<<<nbkt, 256, 0, stream>>>(packed, Hs, bsum, rowptr, dinv, csr,
                                          E, N, nbkt, nchunk, nscan);

    // ---- layer 1 (wide grid) + aggregate; layers 2/3 MFMA + aggregate
    k_gemm7<<<nb_gemm7, 256, 0, stream>>>(x, W1, dinv, bufH, N);
    k_aggregate<<<nb_agg, 256, 0, stream>>>(rowptr, csr, bufH, b1, dinv, bufA, N);
    k_gemm_mfma<<<nb_mfma, 256, 0, stream>>>(bufA, Wf2, dinv, bufH, N);
    k_aggregate<<<nb_agg, 256, 0, stream>>>(rowptr, csr, bufH, b2, dinv, bufA, N);
    k_gemm_mfma<<<nb_mfma, 256, 0, stream>>>(bufA, Wf3, dinv, bufH, N);
    k_aggregate<<<nb_agg, 256, 0, stream>>>(rowptr, csr, bufH, b3, dinv, bufA, N);

    // ---- fused mean-pool + head (one block per graph)
    k_pool_head<<<NGRAPHS, 256, 0, stream>>>(bufA, batch, Wl, bl, out, N);
}

// Round 16
// 269.861 us; speedup vs baseline: 3.5140x; 1.0650x over previous
//
#include <hip/hip_runtime.h>
#include <hip/hip_fp16.h>

#define HID 64
#define NGRAPHS 256
#define CHUNK 8192        // edges per pass-1 chunk
#define BKTSZ 512         // nodes per coarse bucket
#define BKTSH 9
#define PSH 17            // src fits in 17 bits (N <= 131072)
#define PMASK 0x1FFFF

typedef _Float16 half8 __attribute__((ext_vector_type(8)));
typedef float f32x4 __attribute__((ext_vector_type(4)));

// MEASURED LAWS (R1-R15):
//  - scattered device-scope atomics/stores write through ~64B lines at
//    ~0.9 TB/s, parallelism/padding-invariant -> LDS counting-sort CSR.
//  - grid.sync() coop barrier ~100us at full grid (R13: 948us total) ->
//    discrete launches (~6-7us/boundary) are strictly cheaper here.
//  - R14: fusing wide gemm7 into 196-block csr_build serialized it
//    (6.6% occupancy, +30us) -> keep wide phases on wide grids.
//  - R15: 16-wide agg unroll (+48 VGPR in hot kernel) cost ~16us vs
//    8-wide; mean deg 12.5 rarely fills 16 -> 8-wide is the sweet spot.

// ---- P0: prepW (blocks 0-1) + per-chunk coarse histogram ----------------

__global__ __launch_bounds__(256) void k_hist(
        const int* __restrict__ dst, const float* __restrict__ W2,
        const float* __restrict__ W3, __half* __restrict__ Wf2,
        __half* __restrict__ Wf3, int* __restrict__ H,
        int e, int nbkt, int nchunk) {
    __shared__ int cnt[256];
    const int t = threadIdx.x, b = blockIdx.x;
    const int gtid = b * 256 + t;
    if (gtid < 512) {       // W fragment repack: 16x16x32-f16 B layout
        int p = gtid;
        int kt = p >> 8, c = (p >> 6) & 3, lane = p & 63;
        int quad = lane >> 4, m = lane & 15;
#pragma unroll
        for (int j = 0; j < 8; ++j) {
            int k = kt * 32 + quad * 8 + j;
            int ch = c * 16 + m;
            Wf2[(size_t)p * 8 + j] = __float2half(W2[k * HID + ch]);
            Wf3[(size_t)p * 8 + j] = __float2half(W3[k * HID + ch]);
        }
    }
    for (int i = t; i < nbkt; i += 256) cnt[i] = 0;
    __syncthreads();
#pragma unroll
    for (int it = 0; it < CHUNK / 1024; ++it) {
        int idx = b * CHUNK + it * 1024 + t * 4;
        if (idx + 3 < e) {
            int4 d = *(const int4*)(dst + idx);
            atomicAdd(&cnt[d.x >> BKTSH], 1);
            atomicAdd(&cnt[d.y >> BKTSH], 1);
            atomicAdd(&cnt[d.z >> BKTSH], 1);
            atomicAdd(&cnt[d.w >> BKTSH], 1);
        } else {
            for (int i = idx; i < e && i < idx + 4; ++i)
                atomicAdd(&cnt[dst[i] >> BKTSH], 1);
        }
    }
    __syncthreads();
    for (int i = t; i < nbkt; i += 256) H[i * nchunk + b] = cnt[i];
}

// ---- P1: per-1024 partial exclusive scans + block sums ------------------

__global__ __launch_bounds__(256) void k_scan(const int* __restrict__ in,
                                              int* __restrict__ outp,
                                              int* __restrict__ bsum, int n) {
    __shared__ int sh[256];
    const int t = threadIdx.x;
    const int base = blockIdx.x * 1024 + t * 4;
    int v[4];
    int s = 0;
#pragma unroll
    for (int k = 0; k < 4; k++) {
        int i = base + k;
        v[k] = (i < n) ? in[i] : 0;
        s += v[k];
    }
    sh[t] = s;
    __syncthreads();
#pragma unroll
    for (int off = 1; off < 256; off <<= 1) {
        int add = (t >= off) ? sh[t - off] : 0;
        __syncthreads();
        sh[t] += add;
        __syncthreads();
    }
    int run = sh[t] - s;
#pragma unroll
    for (int k = 0; k < 4; k++) {
        int i = base + k;
        if (i < n) outp[i] = run;
        run += v[k];
    }
    if (t == 255) bsum[blockIdx.x] = sh[255];
}

// ---- P2: bucket scatter (packed 4B, coalesced runs) ---------------------

__global__ __launch_bounds__(256) void k_scatter(
        const int* __restrict__ src, const int* __restrict__ dst,
        const int* __restrict__ Hs, const int* __restrict__ bsum,
        int* __restrict__ packed, int e, int nbkt, int nchunk, int nscan) {
    __shared__ int off[256];
    __shared__ int lc[256];
    __shared__ int bpref[32];
    const int t = threadIdx.x, b = blockIdx.x;
    if (t == 0) {
        int run = 0;
        for (int i = 0; i < nscan; ++i) { bpref[i] = run; run += bsum[i]; }
    }
    __syncthreads();
    for (int i = t; i < nbkt; i += 256) {
        int idx = i * nchunk + b;
        off[i] = Hs[idx] + bpref[idx >> 10];
        lc[i] = 0;
    }
    __syncthreads();
#pragma unroll
    for (int it = 0; it < CHUNK / 1024; ++it) {
        int idx = b * CHUNK + it * 1024 + t * 4;
        if (idx + 3 < e) {
            int4 d = *(const int4*)(dst + idx);
            int4 s = *(const int4*)(src + idx);
            int b0 = d.x >> BKTSH, b1 = d.y >> BKTSH;
            int b2 = d.z >> BKTSH, b3 = d.w >> BKTSH;
            int r0 = atomicAdd(&lc[b0], 1);
            int r1 = atomicAdd(&lc[b1], 1);
            int r2 = atomicAdd(&lc[b2], 1);
            int r3 = atomicAdd(&lc[b3], 1);
            packed[off[b0] + r0] = s.x | ((d.x & (BKTSZ - 1)) << PSH);
            packed[off[b1] + r1] = s.y | ((d.y & (BKTSZ - 1)) << PSH);
            packed[off[b2] + r2] = s.z | ((d.z & (BKTSZ - 1)) << PSH);
            packed[off[b3] + r3] = s.w | ((d.w & (BKTSZ - 1)) << PSH);
        } else {
            for (int i = idx; i < e && i < idx + 4; ++i) {
                int dd = dst[i];
                int bk = dd >> BKTSH;
                int r = atomicAdd(&lc[bk], 1);
                packed[off[bk] + r] = src[i] | ((dd & (BKTSZ - 1)) << PSH);
            }
        }
    }
}

// ---- P3: per-bucket local CSR build (196 blocks, CSR work ONLY) ---------

__global__ __launch_bounds__(256) void k_csr_build(
        const int* __restrict__ packed, const int* __restrict__ Hs,
        const int* __restrict__ bsum, int* __restrict__ rowptr,
        float* __restrict__ dinv, int* __restrict__ csr,
        int e, int n, int nbkt, int nchunk, int nscan) {
    __shared__ int cnt[BKTSZ];
    __shared__ int pref[BKTSZ];
    __shared__ int ssum[256];
    __shared__ int cnt2[BKTSZ];
    __shared__ int bpref[32];
    const int t = threadIdx.x, bkt = blockIdx.x;
    if (t == 0) {
        int run = 0;
        for (int i = 0; i < nscan; ++i) { bpref[i] = run; run += bsum[i]; }
    }
    if (bkt == 0 && t == 0) rowptr[n] = e;
    cnt[t] = 0; cnt[t + 256] = 0;
    cnt2[t] = 0; cnt2[t + 256] = 0;
    __syncthreads();
    int i0 = bkt * nchunk;
    int segStart = Hs[i0] + bpref[i0 >> 10];
    int segEnd = e;
    if (bkt + 1 < nbkt) {
        int i1 = (bkt + 1) * nchunk;
        segEnd = Hs[i1] + bpref[i1 >> 10];
    }
    for (int j = segStart + t; j < segEnd; j += 256)
        atomicAdd(&cnt[(packed[j] >> PSH) & (BKTSZ - 1)], 1);
    __syncthreads();
    int a0 = cnt[2 * t], a1 = cnt[2 * t + 1];
    int s = a0 + a1;
    ssum[t] = s;
    __syncthreads();
#pragma unroll
    for (int off = 1; off < 256; off <<= 1) {
        int add = (t >= off) ? ssum[t - off] : 0;
        __syncthreads();
        ssum[t] += add;
        __syncthreads();
    }
    int p = ssum[t] - s;
    pref[2 * t] = p;
    pref[2 * t + 1] = p + a0;
    __syncthreads();
    for (int i = t; i < BKTSZ; i += 256) {
        int node = bkt * BKTSZ + i;
        if (node < n) {
            rowptr[node] = segStart + pref[i];
            dinv[node] = rsqrtf((float)(cnt[i] + 1));   // +1 self-loop
        }
    }
    for (int j = segStart + t; j < segEnd; j += 256) {
        int pk = packed[j];
        int ld = (pk >> PSH) & (BKTSZ - 1);
        int r = atomicAdd(&cnt2[ld], 1);
        csr[segStart + pref[ld] + r] = pk & PMASK;
    }
}

// ---- layer-1 gemm (K=7, fp32 in, WIDE grid): h' = (x @ W1) * dinv -------

__global__ __launch_bounds__(256) void k_gemm7(
        const float* __restrict__ act, const float* __restrict__ W,
        const float* __restrict__ dinv, __half* __restrict__ h, int n_nodes) {
    __shared__ float Wsh[7 * HID];
    __shared__ float Ash[16 * 7];
    const int t = threadIdx.x;
    const int n0 = blockIdx.x * 16;

    for (int i = t; i < 7 * HID; i += 256) Wsh[i] = W[i];
    const long long lim = (long long)(n_nodes - n0) * 7;
    for (int i = t; i < 16 * 7; i += 256)
        Ash[i] = (i < lim) ? act[(size_t)n0 * 7 + i] : 0.0f;
    __syncthreads();

    const int c = t & 63;
    const int g = t >> 6;
    float acc[4] = {0.0f, 0.0f, 0.0f, 0.0f};
#pragma unroll
    for (int k = 0; k < 7; k++) {
        float w = Wsh[k * HID + c];
#pragma unroll
        for (int i = 0; i < 4; i++) acc[i] += Ash[(g * 4 + i) * 7 + k] * w;
    }
#pragma unroll
    for (int i = 0; i < 4; i++) {
        int n = n0 + g * 4 + i;
        if (n < n_nodes) h[(size_t)n * HID + c] = __float2half(acc[i] * dinv[n]);
    }
}

// ---- CSR aggregate: weightless, 8/4-wide (R11-proven), fp16 in/out ------
// agg = b + dv*(h'[d] + sum h'[s]); fp32 accumulation.

__device__ __forceinline__ float4 h4_to_f4(int2 raw) {
    __half2 p0 = *(__half2*)&raw.x;
    __half2 p1 = *(__half2*)&raw.y;
    float2 f0 = __half22float2(p0);
    float2 f1 = __half22float2(p1);
    return make_float4(f0.x, f0.y, f1.x, f1.y);
}

__global__ __launch_bounds__(256) void k_aggregate(
        const int* __restrict__ rowptr, const int* __restrict__ csr,
        const __half* __restrict__ h, const float* __restrict__ b,
        const float* __restrict__ dinv, __half* __restrict__ agg, int n_nodes) {
    int node = blockIdx.x * 16 + (threadIdx.x >> 4);
    int l16 = threadIdx.x & 15;
    if (node >= n_nodes) return;
    int beg = rowptr[node], end = rowptr[node + 1];
    const int2* h8 = (const int2*)h;
    const float4* b4 = (const float4*)b;
    float dv = dinv[node];
    float4 inner = h4_to_f4(h8[(size_t)node * 16 + l16]);   // self h'
    int j = beg;
    for (; j + 7 < end; j += 8) {                  // 8 outstanding gathers
        int s[8];
#pragma unroll
        for (int q = 0; q < 8; ++q) s[q] = csr[j + q];
        int2 r[8];
#pragma unroll
        for (int q = 0; q < 8; ++q) r[q] = h8[(size_t)s[q] * 16 + l16];
#pragma unroll
        for (int q = 0; q < 8; ++q) {
            float4 v = h4_to_f4(r[q]);
            inner.x += v.x; inner.y += v.y; inner.z += v.z; inner.w += v.w;
        }
    }
    for (; j + 3 < end; j += 4) {
        int s0 = csr[j], s1 = csr[j + 1], s2 = csr[j + 2], s3 = csr[j + 3];
        float4 v0 = h4_to_f4(h8[(size_t)s0 * 16 + l16]);
        float4 v1 = h4_to_f4(h8[(size_t)s1 * 16 + l16]);
        float4 v2 = h4_to_f4(h8[(size_t)s2 * 16 + l16]);
        float4 v3 = h4_to_f4(h8[(size_t)s3 * 16 + l16]);
        inner.x += v0.x + v1.x + v2.x + v3.x;
        inner.y += v0.y + v1.y + v2.y + v3.y;
        inner.z += v0.z + v1.z + v2.z + v3.z;
        inner.w += v0.w + v1.w + v2.w + v3.w;
    }
    for (; j < end; j++) {
        float4 v = h4_to_f4(h8[(size_t)csr[j] * 16 + l16]);
        inner.x += v.x; inner.y += v.y; inner.z += v.z; inner.w += v.w;
    }
    float4 bb = b4[l16];
    __half2 q0 = __floats2half2_rn(bb.x + dv * inner.x, bb.y + dv * inner.y);
    __half2 q1 = __floats2half2_rn(bb.z + dv * inner.z, bb.w + dv * inner.w);
    int2 outv;
    outv.x = *(int*)&q0;
    outv.y = *(int*)&q1;
    ((int2*)agg)[(size_t)node * 16 + l16] = outv;
}

// ---- layers 2/3: MFMA gemm, no LDS: h' = (relu(act) @ W) * dinv ---------
// A-frag: lane holds act[n0+(lane&15)][kt*32+(lane>>4)*8+j] (16B load).
// D: col=lane&15 (ch), row=(lane>>4)*4+reg (node). [verified R10/R11]

__global__ __launch_bounds__(256) void k_gemm_mfma(
        const __half* __restrict__ act, const __half* __restrict__ Wf,
        const float* __restrict__ dinv, __half* __restrict__ h, int n_nodes) {
    const int wave = threadIdx.x >> 6;
    const int lane = threadIdx.x & 63;
    const int quad = lane >> 4, m = lane & 15;
    const int n0 = blockIdx.x * 64 + wave * 16;
    if (n0 >= n_nodes) return;            // wave-uniform
    const half8* Wf8 = (const half8*)Wf;
    f32x4 zero = {0.0f, 0.0f, 0.0f, 0.0f};
    f32x4 acc[4] = {zero, zero, zero, zero};
#pragma unroll
    for (int kt = 0; kt < 2; ++kt) {
        half8 av = *(const half8*)(act + (size_t)(n0 + m) * HID + kt * 32 + quad * 8);
#pragma unroll
        for (int j = 0; j < 8; ++j)
            av[j] = av[j] > (_Float16)0 ? av[j] : (_Float16)0;
#pragma unroll
        for (int c = 0; c < 4; ++c) {
            half8 bv = Wf8[(kt * 4 + c) * 64 + lane];
            acc[c] = __builtin_amdgcn_mfma_f32_16x16x32_f16(av, bv, acc[c], 0, 0, 0);
        }
    }
#pragma unroll
    for (int r = 0; r < 4; ++r) {
        int node = n0 + quad * 4 + r;
        if (node < n_nodes) {
            float dv = dinv[node];
#pragma unroll
            for (int c = 0; c < 4; ++c)
                h[(size_t)node * HID + c * 16 + m] = __float2half(acc[c][r] * dv);
        }
    }
}

// ---- fused mean-pool + head: one block per graph, batch sorted ----------

__global__ __launch_bounds__(256) void k_pool_head(
        const __half* __restrict__ agg, const int* __restrict__ batch,
        const float* __restrict__ Wl, const float* __restrict__ bl,
        float* __restrict__ out, int n_nodes) {
    int g = blockIdx.x;
    int lo = 0, hi = n_nodes;
    while (lo < hi) { int m = (lo + hi) >> 1; if (batch[m] < g) lo = m + 1; else hi = m; }
    int nstart = lo;
    hi = n_nodes;
    while (lo < hi) { int m = (lo + hi) >> 1; if (batch[m] < g + 1) lo = m + 1; else hi = m; }
    int nend = lo;

    int c = threadIdx.x & 63, part = threadIdx.x >> 6;
    float acc = 0.0f;
    for (int n = nstart + part; n < nend; n += 4)
        acc += __half2float(agg[(size_t)n * HID + c]);

    __shared__ float red[4][64];
    __shared__ float hd[128];
    red[part][c] = acc;
    __syncthreads();
    if (threadIdx.x < 64) {
        float cntf = (float)(nend - nstart);
        float pooled = (red[0][c] + red[1][c] + red[2][c] + red[3][c])
                       / fmaxf(cntf, 1.0f);
        hd[c] = pooled * Wl[c * 2 + 0];
        hd[64 + c] = pooled * Wl[c * 2 + 1];
    }
    __syncthreads();
    if (threadIdx.x < 2) {
        float s = 0.0f;
        for (int k = 0; k < 64; k++) s += hd[threadIdx.x * 64 + k];
        out[g * 2 + threadIdx.x] = s + bl[threadIdx.x];
    }
}

// -------------------------------------------------------------------------

extern "C" void kernel_launch(void* const* d_in, const int* in_sizes, int n_in,
                              void* d_out, int out_size, void* d_ws, size_t ws_size,
                              hipStream_t stream) {
    const float* x     = (const float*)d_in[0];
    const int*   ei    = (const int*)d_in[1];
    const int*   batch = (const int*)d_in[2];
    const float* W1    = (const float*)d_in[3];
    const float* b1    = (const float*)d_in[4];
    const float* W2    = (const float*)d_in[5];
    const float* b2    = (const float*)d_in[6];
    const float* W3    = (const float*)d_in[7];
    const float* b3    = (const float*)d_in[8];
    const float* Wl    = (const float*)d_in[9];
    const float* bl    = (const float*)d_in[10];
    float* out = (float*)d_out;

    const int N = in_sizes[0] / 7;     // 100000
    const int E = in_sizes[1] / 2;     // 1250000
    const int* src = ei;
    const int* dst = ei + E;

    const int nbkt   = (N + BKTSZ - 1) >> BKTSH;          // 196
    const int nchunk = (E + CHUNK - 1) / CHUNK;           // 153
    const int lenH   = nbkt * nchunk;
    const int nscan  = (lenH + 1023) / 1024;              // 30 (<=32)

    char* ws = (char*)d_ws;
    size_t off = 0;
    auto carve = [&](size_t bytes) {
        void* p = ws + off;
        off = (off + bytes + 255) & ~(size_t)255;
        return p;
    };
    int*    H      = (int*)carve((size_t)lenH * 4);
    int*    Hs     = (int*)carve((size_t)lenH * 4);
    int*    bsum   = (int*)carve(512 * 4);
    int*    packed = (int*)carve((size_t)E * 4);
    int*    csr    = (int*)carve((size_t)E * 4);
    int*    rowptr = (int*)carve((size_t)(N + 1) * 4);
    float*  dinv   = (float*)carve((size_t)N * 4);
    __half* Wf2    = (__half*)carve(4096 * 2);
    __half* Wf3    = (__half*)carve(4096 * 2);
    __half* bufH   = (__half*)carve((size_t)(N + 64) * HID * 2);  // +pad rows
    __half* bufA   = (__half*)carve((size_t)(N + 64) * HID * 2);

    const int nb_gemm7 = (N + 15) / 16;    // 6250
    const int nb_agg   = (N + 15) / 16;    // 6250
    const int nb_mfma  = (N + 63) / 64;    // 1563

    // ---- CSR build (LDS counting sort)
    k_hist<<<nchunk, 256, 0, stream>>>(dst, W2, W3, Wf2, Wf3, H, E, nbkt, nchunk);
    k_scan<<<nscan, 256, 0, stream>>>(H, Hs, bsum, lenH);
    k_scatter<<<nchunk, 256, 0, stream>>>(src, dst, Hs, bsum, packed,
                                          E, nbkt, nchunk, nscan);
    k_csr_build<<<nbkt, 256, 0, stream>>>(packed, Hs, bsum, rowptr, dinv, csr,
                                          E, N, nbkt, nchunk, nscan);

    // ---- layer 1 (wide grid) + aggregate; layers 2/3 MFMA + aggregate
    k_gemm7<<<nb_gemm7, 256, 0, stream>>>(x, W1, dinv, bufH, N);
    k_aggregate<<<nb_agg, 256, 0, stream>>>(rowptr, csr, bufH, b1, dinv, bufA, N);
    k_gemm_mfma<<<nb_mfma, 256, 0, stream>>>(bufA, Wf2, dinv, bufH, N);
    k_aggregate<<<nb_agg, 256, 0, stream>>>(rowptr, csr, bufH, b2, dinv, bufA, N);
    k_gemm_mfma<<<nb_mfma, 256, 0, stream>>>(bufA, Wf3, dinv, bufH, N);
    k_aggregate<<<nb_agg, 256, 0, stream>>>(rowptr, csr, bufH, b3, dinv, bufA, N);

    // ---- fused mean-pool + head (one block per graph)
    k_pool_head<<<NGRAPHS, 256, 0, stream>>>(bufA, batch, Wl, bl, out, N);
}

// Round 17
// 257.730 us; speedup vs baseline: 3.6794x; 1.0471x over previous
//
#include <hip/hip_runtime.h>
#include <hip/hip_fp16.h>

#define HID 64
#define NGRAPHS 256
#define CHUNK 8192        // edges per pass-1 chunk
#define BKTSZ 512         // nodes per coarse bucket
#define BKTSH 9
#define PSH 17            // src fits in 17 bits (N <= 131072)
#define PMASK 0x1FFFF

typedef _Float16 half8 __attribute__((ext_vector_type(8)));
typedef float f32x4 __attribute__((ext_vector_type(4)));

// MEASURED LAWS (R1-R16):
//  - scattered device-scope atomics/stores write through ~64B lines at
//    ~0.9 TB/s, parallelism/padding-invariant -> LDS counting-sort CSR.
//  - grid.sync() coop barrier ~100us at full grid (R13) -> discrete
//    launches (~6-7us/boundary) are strictly cheaper here.
//  - R14: fusing wide gemm7 into 196-block csr_build serialized it ->
//    keep wide phases on wide grids (R17 fusion keeps the 6250-block grid).
//  - R15: 16-wide agg unroll regressed (+48 VGPR); 8-wide is the max.

// ---- P0: prepW (blocks 0-1) + per-chunk coarse histogram ----------------

__global__ __launch_bounds__(256) void k_hist(
        const int* __restrict__ dst, const float* __restrict__ W2,
        const float* __restrict__ W3, __half* __restrict__ Wf2,
        __half* __restrict__ Wf3, int* __restrict__ H,
        int e, int nbkt, int nchunk) {
    __shared__ int cnt[256];
    const int t = threadIdx.x, b = blockIdx.x;
    const int gtid = b * 256 + t;
    if (gtid < 512) {       // W fragment repack: 16x16x32-f16 B layout
        int p = gtid;
        int kt = p >> 8, c = (p >> 6) & 3, lane = p & 63;
        int quad = lane >> 4, m = lane & 15;
#pragma unroll
        for (int j = 0; j < 8; ++j) {
            int k = kt * 32 + quad * 8 + j;
            int ch = c * 16 + m;
            Wf2[(size_t)p * 8 + j] = __float2half(W2[k * HID + ch]);
            Wf3[(size_t)p * 8 + j] = __float2half(W3[k * HID + ch]);
        }
    }
    for (int i = t; i < nbkt; i += 256) cnt[i] = 0;
    __syncthreads();
#pragma unroll
    for (int it = 0; it < CHUNK / 1024; ++it) {
        int idx = b * CHUNK + it * 1024 + t * 4;
        if (idx + 3 < e) {
            int4 d = *(const int4*)(dst + idx);
            atomicAdd(&cnt[d.x >> BKTSH], 1);
            atomicAdd(&cnt[d.y >> BKTSH], 1);
            atomicAdd(&cnt[d.z >> BKTSH], 1);
            atomicAdd(&cnt[d.w >> BKTSH], 1);
        } else {
            for (int i = idx; i < e && i < idx + 4; ++i)
                atomicAdd(&cnt[dst[i] >> BKTSH], 1);
        }
    }
    __syncthreads();
    for (int i = t; i < nbkt; i += 256) H[i * nchunk + b] = cnt[i];
}

// ---- P1: per-1024 partial exclusive scans + block sums ------------------

__global__ __launch_bounds__(256) void k_scan(const int* __restrict__ in,
                                              int* __restrict__ outp,
                                              int* __restrict__ bsum, int n) {
    __shared__ int sh[256];
    const int t = threadIdx.x;
    const int base = blockIdx.x * 1024 + t * 4;
    int v[4];
    int s = 0;
#pragma unroll
    for (int k = 0; k < 4; k++) {
        int i = base + k;
        v[k] = (i < n) ? in[i] : 0;
        s += v[k];
    }
    sh[t] = s;
    __syncthreads();
#pragma unroll
    for (int off = 1; off < 256; off <<= 1) {
        int add = (t >= off) ? sh[t - off] : 0;
        __syncthreads();
        sh[t] += add;
        __syncthreads();
    }
    int run = sh[t] - s;
#pragma unroll
    for (int k = 0; k < 4; k++) {
        int i = base + k;
        if (i < n) outp[i] = run;
        run += v[k];
    }
    if (t == 255) bsum[blockIdx.x] = sh[255];
}

// ---- P2: bucket scatter (packed 4B, coalesced runs) ---------------------

__global__ __launch_bounds__(256) void k_scatter(
        const int* __restrict__ src, const int* __restrict__ dst,
        const int* __restrict__ Hs, const int* __restrict__ bsum,
        int* __restrict__ packed, int e, int nbkt, int nchunk, int nscan) {
    __shared__ int off[256];
    __shared__ int lc[256];
    __shared__ int bpref[32];
    const int t = threadIdx.x, b = blockIdx.x;
    if (t == 0) {
        int run = 0;
        for (int i = 0; i < nscan; ++i) { bpref[i] = run; run += bsum[i]; }
    }
    __syncthreads();
    for (int i = t; i < nbkt; i += 256) {
        int idx = i * nchunk + b;
        off[i] = Hs[idx] + bpref[idx >> 10];
        lc[i] = 0;
    }
    __syncthreads();
#pragma unroll
    for (int it = 0; it < CHUNK / 1024; ++it) {
        int idx = b * CHUNK + it * 1024 + t * 4;
        if (idx + 3 < e) {
            int4 d = *(const int4*)(dst + idx);
            int4 s = *(const int4*)(src + idx);
            int b0 = d.x >> BKTSH, b1 = d.y >> BKTSH;
            int b2 = d.z >> BKTSH, b3 = d.w >> BKTSH;
            int r0 = atomicAdd(&lc[b0], 1);
            int r1 = atomicAdd(&lc[b1], 1);
            int r2 = atomicAdd(&lc[b2], 1);
            int r3 = atomicAdd(&lc[b3], 1);
            packed[off[b0] + r0] = s.x | ((d.x & (BKTSZ - 1)) << PSH);
            packed[off[b1] + r1] = s.y | ((d.y & (BKTSZ - 1)) << PSH);
            packed[off[b2] + r2] = s.z | ((d.z & (BKTSZ - 1)) << PSH);
            packed[off[b3] + r3] = s.w | ((d.w & (BKTSZ - 1)) << PSH);
        } else {
            for (int i = idx; i < e && i < idx + 4; ++i) {
                int dd = dst[i];
                int bk = dd >> BKTSH;
                int r = atomicAdd(&lc[bk], 1);
                packed[off[bk] + r] = src[i] | ((dd & (BKTSZ - 1)) << PSH);
            }
        }
    }
}

// ---- P3: per-bucket local CSR build (196 blocks, CSR work ONLY) ---------

__global__ __launch_bounds__(256) void k_csr_build(
        const int* __restrict__ packed, const int* __restrict__ Hs,
        const int* __restrict__ bsum, int* __restrict__ rowptr,
        float* __restrict__ dinv, int* __restrict__ csr,
        int e, int n, int nbkt, int nchunk, int nscan) {
    __shared__ int cnt[BKTSZ];
    __shared__ int pref[BKTSZ];
    __shared__ int ssum[256];
    __shared__ int cnt2[BKTSZ];
    __shared__ int bpref[32];
    const int t = threadIdx.x, bkt = blockIdx.x;
    if (t == 0) {
        int run = 0;
        for (int i = 0; i < nscan; ++i) { bpref[i] = run; run += bsum[i]; }
    }
    if (bkt == 0 && t == 0) rowptr[n] = e;
    cnt[t] = 0; cnt[t + 256] = 0;
    cnt2[t] = 0; cnt2[t + 256] = 0;
    __syncthreads();
    int i0 = bkt * nchunk;
    int segStart = Hs[i0] + bpref[i0 >> 10];
    int segEnd = e;
    if (bkt + 1 < nbkt) {
        int i1 = (bkt + 1) * nchunk;
        segEnd = Hs[i1] + bpref[i1 >> 10];
    }
    for (int j = segStart + t; j < segEnd; j += 256)
        atomicAdd(&cnt[(packed[j] >> PSH) & (BKTSZ - 1)], 1);
    __syncthreads();
    int a0 = cnt[2 * t], a1 = cnt[2 * t + 1];
    int s = a0 + a1;
    ssum[t] = s;
    __syncthreads();
#pragma unroll
    for (int off = 1; off < 256; off <<= 1) {
        int add = (t >= off) ? ssum[t - off] : 0;
        __syncthreads();
        ssum[t] += add;
        __syncthreads();
    }
    int p = ssum[t] - s;
    pref[2 * t] = p;
    pref[2 * t + 1] = p + a0;
    __syncthreads();
    for (int i = t; i < BKTSZ; i += 256) {
        int node = bkt * BKTSZ + i;
        if (node < n) {
            rowptr[node] = segStart + pref[i];
            dinv[node] = rsqrtf((float)(cnt[i] + 1));   // +1 self-loop
        }
    }
    for (int j = segStart + t; j < segEnd; j += 256) {
        int pk = packed[j];
        int ld = (pk >> PSH) & (BKTSZ - 1);
        int r = atomicAdd(&cnt2[ld], 1);
        csr[segStart + pref[ld] + r] = pk & PMASK;
    }
}

// ---- layer-1 gemm (K=7, fp32 in, WIDE grid): h' = (x @ W1) * dinv -------

__global__ __launch_bounds__(256) void k_gemm7(
        const float* __restrict__ act, const float* __restrict__ W,
        const float* __restrict__ dinv, __half* __restrict__ h, int n_nodes) {
    __shared__ float Wsh[7 * HID];
    __shared__ float Ash[16 * 7];
    const int t = threadIdx.x;
    const int n0 = blockIdx.x * 16;

    for (int i = t; i < 7 * HID; i += 256) Wsh[i] = W[i];
    const long long lim = (long long)(n_nodes - n0) * 7;
    for (int i = t; i < 16 * 7; i += 256)
        Ash[i] = (i < lim) ? act[(size_t)n0 * 7 + i] : 0.0f;
    __syncthreads();

    const int c = t & 63;
    const int g = t >> 6;
    float acc[4] = {0.0f, 0.0f, 0.0f, 0.0f};
#pragma unroll
    for (int k = 0; k < 7; k++) {
        float w = Wsh[k * HID + c];
#pragma unroll
        for (int i = 0; i < 4; i++) acc[i] += Ash[(g * 4 + i) * 7 + k] * w;
    }
#pragma unroll
    for (int i = 0; i < 4; i++) {
        int n = n0 + g * 4 + i;
        if (n < n_nodes) h[(size_t)n * HID + c] = __float2half(acc[i] * dinv[n]);
    }
}

__device__ __forceinline__ float4 h4_to_f4(int2 raw) {
    __half2 p0 = *(__half2*)&raw.x;
    __half2 p1 = *(__half2*)&raw.y;
    float2 f0 = __half22float2(p0);
    float2 f1 = __half22float2(p1);
    return make_float4(f0.x, f0.y, f1.x, f1.y);
}

// ---- FUSED aggregate + MFMA gemm (layers 1->2, 2->3) --------------------
// Block = 16 nodes. Aggregate (8-wide gathers, b+dv*inner), relu, stage
// act tile in LDS (stride 72 halves: pads b128 reads to 2-way-free), then
// each wave MFMAs its 16-out-ch slice: hout = (act @ Wf) * dinv. Same wide
// grid as plain aggregate (R14 lesson); saves the agg buffer round-trip.

__global__ __launch_bounds__(256) void k_agg_gemm(
        const int* __restrict__ rowptr, const int* __restrict__ csr,
        const __half* __restrict__ h, const float* __restrict__ b,
        const float* __restrict__ dinv, const __half* __restrict__ Wf,
        __half* __restrict__ hout, int n_nodes) {
    __shared__ __half act[16 * 72];
    const int t = threadIdx.x;
    const int n0 = blockIdx.x * 16;
    const int nl = t >> 4;          // local node 0..15
    const int node = n0 + nl;
    const int l16 = t & 15;
    const int2* h8 = (const int2*)h;
    const float4* b4 = (const float4*)b;

    float4 av = make_float4(0.0f, 0.0f, 0.0f, 0.0f);
    if (node < n_nodes) {
        int beg = rowptr[node], end = rowptr[node + 1];
        float dv = dinv[node];
        float4 inner = h4_to_f4(h8[(size_t)node * 16 + l16]);   // self h'
        int j = beg;
        for (; j + 7 < end; j += 8) {              // 8 outstanding gathers
            int s[8];
#pragma unroll
            for (int q = 0; q < 8; ++q) s[q] = csr[j + q];
            int2 r[8];
#pragma unroll
            for (int q = 0; q < 8; ++q) r[q] = h8[(size_t)s[q] * 16 + l16];
#pragma unroll
            for (int q = 0; q < 8; ++q) {
                float4 v = h4_to_f4(r[q]);
                inner.x += v.x; inner.y += v.y; inner.z += v.z; inner.w += v.w;
            }
        }
        for (; j + 3 < end; j += 4) {
            int s0 = csr[j], s1 = csr[j + 1], s2 = csr[j + 2], s3 = csr[j + 3];
            float4 v0 = h4_to_f4(h8[(size_t)s0 * 16 + l16]);
            float4 v1 = h4_to_f4(h8[(size_t)s1 * 16 + l16]);
            float4 v2 = h4_to_f4(h8[(size_t)s2 * 16 + l16]);
            float4 v3 = h4_to_f4(h8[(size_t)s3 * 16 + l16]);
            inner.x += v0.x + v1.x + v2.x + v3.x;
            inner.y += v0.y + v1.y + v2.y + v3.y;
            inner.z += v0.z + v1.z + v2.z + v3.z;
            inner.w += v0.w + v1.w + v2.w + v3.w;
        }
        for (; j < end; j++) {
            float4 v = h4_to_f4(h8[(size_t)csr[j] * 16 + l16]);
            inner.x += v.x; inner.y += v.y; inner.z += v.z; inner.w += v.w;
        }
        float4 bb = b4[l16];
        av.x = fmaxf(bb.x + dv * inner.x, 0.0f);   // relu(agg) = gemm input
        av.y = fmaxf(bb.y + dv * inner.y, 0.0f);
        av.z = fmaxf(bb.z + dv * inner.z, 0.0f);
        av.w = fmaxf(bb.w + dv * inner.w, 0.0f);
    }
    {   // stage act tile: row nl, cols l16*4..+3 (8B store)
        __half2 p0 = __floats2half2_rn(av.x, av.y);
        __half2 p1 = __floats2half2_rn(av.z, av.w);
        int2 pk;
        pk.x = *(int*)&p0;
        pk.y = *(int*)&p1;
        *(int2*)&act[nl * 72 + l16 * 4] = pk;
    }
    __syncthreads();

    const int wave = t >> 6, lane = t & 63;
    const int quad = lane >> 4, m = lane & 15;
    const half8* Wf8 = (const half8*)Wf;
    f32x4 acc = {0.0f, 0.0f, 0.0f, 0.0f};
#pragma unroll
    for (int kt = 0; kt < 2; ++kt) {
        half8 a = *(const half8*)&act[m * 72 + kt * 32 + quad * 8];
        half8 bv = Wf8[(kt * 4 + wave) * 64 + lane];
        acc = __builtin_amdgcn_mfma_f32_16x16x32_f16(a, bv, acc, 0, 0, 0);
    }
#pragma unroll
    for (int r = 0; r < 4; ++r) {
        int nd = n0 + quad * 4 + r;
        if (nd < n_nodes)
            hout[(size_t)nd * HID + wave * 16 + m] =
                __float2half(acc[r] * dinv[nd]);
    }
}

// ---- layer-3 aggregate (standalone; pool needs agg), fp16 out -----------

__global__ __launch_bounds__(256) void k_aggregate(
        const int* __restrict__ rowptr, const int* __restrict__ csr,
        const __half* __restrict__ h, const float* __restrict__ b,
        const float* __restrict__ dinv, __half* __restrict__ agg, int n_nodes) {
    int node = blockIdx.x * 16 + (threadIdx.x >> 4);
    int l16 = threadIdx.x & 15;
    if (node >= n_nodes) return;
    int beg = rowptr[node], end = rowptr[node + 1];
    const int2* h8 = (const int2*)h;
    const float4* b4 = (const float4*)b;
    float dv = dinv[node];
    float4 inner = h4_to_f4(h8[(size_t)node * 16 + l16]);   // self h'
    int j = beg;
    for (; j + 7 < end; j += 8) {                  // 8 outstanding gathers
        int s[8];
#pragma unroll
        for (int q = 0; q < 8; ++q) s[q] = csr[j + q];
        int2 r[8];
#pragma unroll
        for (int q = 0; q < 8; ++q) r[q] = h8[(size_t)s[q] * 16 + l16];
#pragma unroll
        for (int q = 0; q < 8; ++q) {
            float4 v = h4_to_f4(r[q]);
            inner.x += v.x; inner.y += v.y; inner.z += v.z; inner.w += v.w;
        }
    }
    for (; j + 3 < end; j += 4) {
        int s0 = csr[j], s1 = csr[j + 1], s2 = csr[j + 2], s3 = csr[j + 3];
        float4 v0 = h4_to_f4(h8[(size_t)s0 * 16 + l16]);
        float4 v1 = h4_to_f4(h8[(size_t)s1 * 16 + l16]);
        float4 v2 = h4_to_f4(h8[(size_t)s2 * 16 + l16]);
        float4 v3 = h4_to_f4(h8[(size_t)s3 * 16 + l16]);
        inner.x += v0.x + v1.x + v2.x + v3.x;
        inner.y += v0.y + v1.y + v2.y + v3.y;
        inner.z += v0.z + v1.z + v2.z + v3.z;
        inner.w += v0.w + v1.w + v2.w + v3.w;
    }
    for (; j < end; j++) {
        float4 v = h4_to_f4(h8[(size_t)csr[j] * 16 + l16]);
        inner.x += v.x; inner.y += v.y; inner.z += v.z; inner.w += v.w;
    }
    float4 bb = b4[l16];
    __half2 q0 = __floats2half2_rn(bb.x + dv * inner.x, bb.y + dv * inner.y);
    __half2 q1 = __floats2half2_rn(bb.z + dv * inner.z, bb.w + dv * inner.w);
    int2 outv;
    outv.x = *(int*)&q0;
    outv.y = *(int*)&q1;
    ((int2*)agg)[(size_t)node * 16 + l16] = outv;
}

// ---- fused mean-pool + head: one block per graph, batch sorted ----------

__global__ __launch_bounds__(256) void k_pool_head(
        const __half* __restrict__ agg, const int* __restrict__ batch,
        const float* __restrict__ Wl, const float* __restrict__ bl,
        float* __restrict__ out, int n_nodes) {
    int g = blockIdx.x;
    int lo = 0, hi = n_nodes;
    while (lo < hi) { int m = (lo + hi) >> 1; if (batch[m] < g) lo = m + 1; else hi = m; }
    int nstart = lo;
    hi = n_nodes;
    while (lo < hi) { int m = (lo + hi) >> 1; if (batch[m] < g + 1) lo = m + 1; else hi = m; }
    int nend = lo;

    int c = threadIdx.x & 63, part = threadIdx.x >> 6;
    float acc = 0.0f;
    for (int n = nstart + part; n < nend; n += 4)
        acc += __half2float(agg[(size_t)n * HID + c]);

    __shared__ float red[4][64];
    __shared__ float hd[128];
    red[part][c] = acc;
    __syncthreads();
    if (threadIdx.x < 64) {
        float cntf = (float)(nend - nstart);
        float pooled = (red[0][c] + red[1][c] + red[2][c] + red[3][c])
                       / fmaxf(cntf, 1.0f);
        hd[c] = pooled * Wl[c * 2 + 0];
        hd[64 + c] = pooled * Wl[c * 2 + 1];
    }
    __syncthreads();
    if (threadIdx.x < 2) {
        float s = 0.0f;
        for (int k = 0; k < 64; k++) s += hd[threadIdx.x * 64 + k];
        out[g * 2 + threadIdx.x] = s + bl[threadIdx.x];
    }
}

// -------------------------------------------------------------------------

extern "C" void kernel_launch(void* const* d_in, const int* in_sizes, int n_in,
                              void* d_out, int out_size, void* d_ws, size_t ws_size,
                              hipStream_t stream) {
    const float* x     = (const float*)d_in[0];
    const int*   ei    = (const int*)d_in[1];
    const int*   batch = (const int*)d_in[2];
    const float* W1    = (const float*)d_in[3];
    const float* b1    = (const float*)d_in[4];
    const float* W2    = (const float*)d_in[5];
    const float* b2    = (const float*)d_in[6];
    const float* W3    = (const float*)d_in[7];
    const float* b3    = (const float*)d_in[8];
    const float* Wl    = (const float*)d_in[9];
    const float* bl    = (const float*)d_in[10];
    float* out = (float*)d_out;

    const int N = in_sizes[0] / 7;     // 100000
    const int E = in_sizes[1] / 2;     // 1250000
    const int* src = ei;
    const int* dst = ei + E;

    const int nbkt   = (N + BKTSZ - 1) >> BKTSH;          // 196
    const int nchunk = (E + CHUNK - 1) / CHUNK;           // 153
    const int lenH   = nbkt * nchunk;
    const int nscan  = (lenH + 1023) / 1024;              // 30 (<=32)

    char* ws = (char*)d_ws;
    size_t off = 0;
    auto carve = [&](size_t bytes) {
        void* p = ws + off;
        off = (off + bytes + 255) & ~(size_t)255;
        return p;
    };
    int*    H      = (int*)carve((size_t)lenH * 4);
    int*    Hs     = (int*)carve((size_t)lenH * 4);
    int*    bsum   = (int*)carve(512 * 4);
    int*    packed = (int*)carve((size_t)E * 4);
    int*    csr    = (int*)carve((size_t)E * 4);
    int*    rowptr = (int*)carve((size_t)(N + 1) * 4);
    float*  dinv   = (float*)carve((size_t)N * 4);
    __half* Wf2    = (__half*)carve(4096 * 2);
    __half* Wf3    = (__half*)carve(4096 * 2);
    __half* bufH   = (__half*)carve((size_t)(N + 64) * HID * 2);  // +pad rows
    __half* bufB   = (__half*)carve((size_t)(N + 64) * HID * 2);

    const int nb_gemm7 = (N + 15) / 16;    // 6250
    const int nb_agg   = (N + 15) / 16;    // 6250

    // ---- CSR build (LDS counting sort)
    k_hist<<<nchunk, 256, 0, stream>>>(dst, W2, W3, Wf2, Wf3, H, E, nbkt, nchunk);
    k_scan<<<nscan, 256, 0, stream>>>(H, Hs, bsum, lenH);
    k_scatter<<<nchunk, 256, 0, stream>>>(src, dst, Hs, bsum, packed,
                                          E, nbkt, nchunk, nscan);
    k_csr_build<<<nbkt, 256, 0, stream>>>(packed, Hs, bsum, rowptr, dinv, csr,
                                          E, N, nbkt, nchunk, nscan);

    // ---- layer 1 gemm; fused agg+gemm x2; layer-3 aggregate
    k_gemm7<<<nb_gemm7, 256, 0, stream>>>(x, W1, dinv, bufH, N);
    k_agg_gemm<<<nb_agg, 256, 0, stream>>>(rowptr, csr, bufH, b1, dinv, Wf2, bufB, N);
    k_agg_gemm<<<nb_agg, 256, 0, stream>>>(rowptr, csr, bufB, b2, dinv, Wf3, bufH, N);
    k_aggregate<<<nb_agg, 256, 0, stream>>>(rowptr, csr, bufH, b3, dinv, bufB, N);

    // ---- fused mean-pool + head (one block per graph)
    k_pool_head<<<NGRAPHS, 256, 0, stream>>>(bufB, batch, Wl, bl, out, N);
}